// Round 2
// baseline (182.386 us; speedup 1.0000x reference)
//
#include <hip/hip_runtime.h>
#include <hip/hip_bf16.h>

// Problem constants: B=4, T=2048, C(n_embd)=1024, H(head)=128
#define Bn 4
#define Tn 2048
#define Cn 1024
#define Hn 128
#define Mn (Bn*Tn)   // 8192 rows of X

typedef _Float16 f16;
typedef __attribute__((ext_vector_type(8))) _Float16 f16x8;  // 8 f16 = 4 VGPRs
typedef __attribute__((ext_vector_type(4))) float f32x4;

// ---------------------------------------------------------------------------
// Kernel 1: transpose + convert weights [C][H] fp32 -> [H][C] fp16 so the
// GEMM B-operand is K-contiguous (NT MFMA pattern). Tiny: ~2.3 MB traffic.
// ---------------------------------------------------------------------------
__global__ void prep_w(const float* __restrict__ Wk, const float* __restrict__ Wq,
                       const float* __restrict__ Wv, f16* __restrict__ Wt) {
    const int w = blockIdx.y;
    const float* W = (w == 0) ? Wk : (w == 1) ? Wq : Wv;
    int idx = blockIdx.x * 256 + threadIdx.x;      // 0 .. C*H-1 (131072)
    int c = idx >> 7;                              // /128
    int h = idx & 127;
    Wt[w * (Cn * Hn) + h * Cn + c] = (f16)W[idx];
}

// ---------------------------------------------------------------------------
// Kernel 2: fused QKV projection GEMM.  proj_w = (X @ W_w + b_w) [* 1/32 for k]
// grid = (Mn/64, 3), 256 threads (4 waves). Tile: BM=64, BN=128(all H), BK=64.
// X is fp32 in HBM; converted to fp16 during LDS staging.
// ---------------------------------------------------------------------------
__global__ __launch_bounds__(256) void qkv_gemm(const float* __restrict__ X,
                                                const f16* __restrict__ Wt,
                                                const float* __restrict__ bk,
                                                const float* __restrict__ bq,
                                                const float* __restrict__ bv,
                                                f16* __restrict__ proj) {
    __shared__ __align__(16) f16 As[64 * 72];   // stride 72: 16B-aligned chunks
    __shared__ __align__(16) f16 Bs[128 * 72];

    const int tid  = threadIdx.x;
    const int w    = blockIdx.y;
    const int r0   = blockIdx.x * 64;
    const int lane = tid & 63, wid = tid >> 6;
    const int quad = lane >> 4, l16 = lane & 15;
    const int wm = wid >> 1, wn = wid & 1;

    const f16*   Ww   = Wt + w * (Cn * Hn);
    const float* bias = (w == 0) ? bk : (w == 1) ? bq : bv;
    const float scale = (w == 0) ? 0.03125f : 1.0f;  // fold C^-0.5 into k (exact)

    f32x4 acc[2][4] = {};

    for (int k0 = 0; k0 < Cn; k0 += 64) {
        // stage A tile: 64 rows x 64 cols, fp32 -> fp16. 512 chunks of 8, 2/thread
        for (int i = 0; i < 2; i++) {
            int ci = tid + 256 * i;
            int row = ci >> 3, cc = ci & 7;
            const float4* p = (const float4*)(X + (r0 + row) * Cn + k0 + cc * 8);
            float4 x0 = p[0], x1 = p[1];
            f16x8 v = { (f16)x0.x, (f16)x0.y, (f16)x0.z, (f16)x0.w,
                        (f16)x1.x, (f16)x1.y, (f16)x1.z, (f16)x1.w };
            *(f16x8*)(&As[row * 72 + cc * 8]) = v;
        }
        // stage B tile: 128 rows x 64 cols fp16, 1024 chunks, 4/thread
        for (int i = 0; i < 4; i++) {
            int ci = tid + 256 * i;
            int row = ci >> 3, cc = ci & 7;
            *(f16x8*)(&Bs[row * 72 + cc * 8]) =
                *(const f16x8*)(Ww + row * Cn + k0 + cc * 8);
        }
        __syncthreads();
        for (int kk = 0; kk < 64; kk += 32) {
            f16x8 af[2], bfv[4];
            for (int mt = 0; mt < 2; mt++) {
                int m = wm * 32 + mt * 16 + l16;
                af[mt] = *(const f16x8*)(&As[m * 72 + kk + quad * 8]);
            }
            for (int nt = 0; nt < 4; nt++) {
                int n = wn * 64 + nt * 16 + l16;
                bfv[nt] = *(const f16x8*)(&Bs[n * 72 + kk + quad * 8]);
            }
            for (int mt = 0; mt < 2; mt++)
                for (int nt = 0; nt < 4; nt++)
                    acc[mt][nt] = __builtin_amdgcn_mfma_f32_16x16x32_f16(
                        af[mt], bfv[nt], acc[mt][nt], 0, 0, 0);
        }
        __syncthreads();
    }

    f16* P = proj + w * (Mn * Hn);
    for (int nt = 0; nt < 4; nt++) {
        int n = wn * 64 + nt * 16 + l16;
        float bv_ = bias[n];
        for (int mt = 0; mt < 2; mt++) {
            for (int r = 0; r < 4; r++) {
                int m = wm * 32 + mt * 16 + quad * 4 + r;  // C/D: row=quad*4+reg
                float val = (acc[mt][nt][r] + bv_) * scale;
                P[(r0 + m) * Hn + n] = (f16)val;
            }
        }
    }
}

// ---------------------------------------------------------------------------
// Kernel 3: flash attention (no mask). out = softmax(k q^T) v, k pre-scaled.
// grid = (Tn/32, Bn) = (64,4) = 256 blocks; 256 threads (4 waves).
// Br=32 query(k)-rows per block, Bc=64 key(q)-rows per iteration.
// Output is fp32.
// ---------------------------------------------------------------------------
__global__ __launch_bounds__(256) void attn_kernel(const f16* __restrict__ proj,
                                                   float* __restrict__ out) {
    __shared__ __align__(16) f16 Ak[32 * 136];   // k rows [32][128] pad->136
    __shared__ __align__(16) f16 Bq[64 * 136];   // q rows [64][128] pad->136
    __shared__ __align__(16) f16 Vt[128 * 72];   // V^T [128][64] pad->72
    __shared__ __align__(16) f16 Pl[32 * 72];    // P f16 [32][64] pad->72
    __shared__ float Sl[32 * 72];                // S fp32 [32][64] pad->72
    __shared__ float mrow[32], lrow[32], arow[32];

    const int tid  = threadIdx.x;
    const int b    = blockIdx.y;
    const int t0   = blockIdx.x * 32;
    const int lane = tid & 63, wid = tid >> 6;
    const int quad = lane >> 4, l16 = lane & 15;
    const int wm = wid >> 1, wn = wid & 1;

    const f16* kp = proj + 0 * (Mn * Hn) + b * Tn * Hn;
    const f16* qp = proj + 1 * (Mn * Hn) + b * Tn * Hn;
    const f16* vp = proj + 2 * (Mn * Hn) + b * Tn * Hn;

    // load Ak once: 32 rows x 16 chunks = 512, 2 per thread
    for (int i = 0; i < 2; i++) {
        int ci = tid + 256 * i;
        int row = ci >> 4, hc = ci & 15;
        *(f16x8*)(&Ak[row * 136 + hc * 8]) =
            *(const f16x8*)(kp + (t0 + row) * Hn + hc * 8);
    }
    if (tid < 32) { mrow[tid] = -1e30f; lrow[tid] = 0.0f; }
    f32x4 accO[4] = {};
    __syncthreads();

    for (int si = 0; si < Tn / 64; si++) {
        const int s0 = si * 64;
        // stage Bq: 64 rows x 16 chunks = 1024, 4 per thread
        for (int i = 0; i < 4; i++) {
            int ci = tid + 256 * i;
            int row = ci >> 4, hc = ci & 15;
            *(f16x8*)(&Bq[row * 136 + hc * 8]) =
                *(const f16x8*)(qp + (s0 + row) * Hn + hc * 8);
        }
        // stage Vt transposed: V^T[h][s] = V[s0+s][h]
        for (int i = 0; i < 4; i++) {
            int ci = tid + 256 * i;
            int s = ci & 63, hc = ci >> 6;
            f16x8 v = *(const f16x8*)(vp + (s0 + s) * Hn + hc * 8);
            for (int j = 0; j < 8; j++) Vt[(hc * 8 + j) * 72 + s] = v[j];
        }
        __syncthreads();

        // S = Ak . Bq^T  (K = H = 128, 4 mfma K-steps)
        f32x4 accS[2] = {};
        for (int kk = 0; kk < 128; kk += 32) {
            f16x8 af = *(const f16x8*)(&Ak[(wm * 16 + l16) * 136 + kk + quad * 8]);
            for (int nt = 0; nt < 2; nt++) {
                int n = (wn * 2 + nt) * 16 + l16;
                f16x8 bfv = *(const f16x8*)(&Bq[n * 136 + kk + quad * 8]);
                accS[nt] = __builtin_amdgcn_mfma_f32_16x16x32_f16(af, bfv, accS[nt], 0, 0, 0);
            }
        }
        for (int nt = 0; nt < 2; nt++) {
            int col = (wn * 2 + nt) * 16 + l16;
            for (int r = 0; r < 4; r++)
                Sl[(wm * 16 + quad * 4 + r) * 72 + col] = accS[nt][r];
        }
        __syncthreads();

        // online softmax: 8 threads per row (same wave -> lockstep, no race)
        {
            int r = tid >> 3, cg = tid & 7;
            float sv[8];
            float mloc = -1e30f;
            for (int j = 0; j < 8; j++) {
                sv[j] = Sl[r * 72 + cg * 8 + j];
                mloc = fmaxf(mloc, sv[j]);
            }
            for (int off = 4; off >= 1; off >>= 1)
                mloc = fmaxf(mloc, __shfl_xor(mloc, off, 8));
            float mold = mrow[r];
            float mnew = fmaxf(mold, mloc);
            float psum = 0.f;
            for (int j = 0; j < 8; j++) {
                float p = __expf(sv[j] - mnew);
                psum += p;
                Pl[r * 72 + cg * 8 + j] = (f16)p;
            }
            for (int off = 4; off >= 1; off >>= 1)
                psum += __shfl_xor(psum, off, 8);
            if (cg == 0) {
                float al = __expf(mold - mnew);
                lrow[r] = lrow[r] * al + psum;
                mrow[r] = mnew;
                arow[r] = al;
            }
        }
        __syncthreads();

        // rescale O by alpha, then O += P . Vt^T  (K = s = 64, 2 mfma K-steps)
        {
            float al[4];
            for (int r = 0; r < 4; r++) al[r] = arow[wm * 16 + quad * 4 + r];
            for (int nt = 0; nt < 4; nt++)
                for (int r = 0; r < 4; r++) accO[nt][r] *= al[r];
        }
        for (int kk = 0; kk < 64; kk += 32) {
            f16x8 af = *(const f16x8*)(&Pl[(wm * 16 + l16) * 72 + kk + quad * 8]);
            for (int nt = 0; nt < 4; nt++) {
                int h = (wn * 4 + nt) * 16 + l16;
                f16x8 bv8 = *(const f16x8*)(&Vt[h * 72 + kk + quad * 8]);
                accO[nt] = __builtin_amdgcn_mfma_f32_16x16x32_f16(af, bv8, accO[nt], 0, 0, 0);
            }
        }
        __syncthreads();
    }

    // epilogue: divide by l, store fp32
    for (int nt = 0; nt < 4; nt++) {
        int h = (wn * 4 + nt) * 16 + l16;
        for (int r = 0; r < 4; r++) {
            int row = wm * 16 + quad * 4 + r;
            float val = accO[nt][r] / lrow[row];
            out[(b * Tn + t0 + row) * Hn + h] = val;
        }
    }
}

extern "C" void kernel_launch(void* const* d_in, const int* in_sizes, int n_in,
                              void* d_out, int out_size, void* d_ws, size_t ws_size,
                              hipStream_t stream) {
    const float* X  = (const float*)d_in[0];
    const float* Wk = (const float*)d_in[1];
    const float* bk = (const float*)d_in[2];
    const float* Wq = (const float*)d_in[3];
    const float* bq = (const float*)d_in[4];
    const float* Wv = (const float*)d_in[5];
    const float* bv = (const float*)d_in[6];
    float* out = (float*)d_out;

    // workspace layout: Wt [3][H][C] f16 (768 KB) | proj [3][M][H] f16 (6 MB)
    f16* Wt   = (f16*)d_ws;
    f16* proj = Wt + 3 * Cn * Hn;

    prep_w<<<dim3(512, 3), 256, 0, stream>>>(Wk, Wq, Wv, Wt);
    qkv_gemm<<<dim3(Mn / 64, 3), 256, 0, stream>>>(X, Wt, bk, bq, bv, proj);
    attn_kernel<<<dim3(Tn / 32, Bn), 256, 0, stream>>>(proj, out);
}

// Round 4
// 146.234 us; speedup vs baseline: 1.2472x; 1.2472x over previous
//
#include <hip/hip_runtime.h>
#include <hip/hip_bf16.h>

// Problem constants: B=4, T=2048, C(n_embd)=1024, H(head)=128
#define Bn 4
#define Tn 2048
#define Cn 1024
#define Hn 128
#define Mn (Bn*Tn)   // 8192 rows of X
#define SCHUNKS 4    // s-split across blocks in attention
#define SCHUNK  (Tn/SCHUNKS)   // 512

typedef _Float16 f16;
typedef __attribute__((ext_vector_type(4))) _Float16 f16x4;  // 2 VGPRs
typedef __attribute__((ext_vector_type(8))) _Float16 f16x8;  // 4 VGPRs
typedef __attribute__((ext_vector_type(4))) float f32x4;

// ---------------------------------------------------------------------------
// Kernel 1: transpose + convert weights [C][H] fp32 -> fused [3*H][C] fp16.
// ---------------------------------------------------------------------------
__global__ void prep_w(const float* __restrict__ Wk, const float* __restrict__ Wq,
                       const float* __restrict__ Wv, f16* __restrict__ Wt) {
    const int w = blockIdx.y;
    const float* W = (w == 0) ? Wk : (w == 1) ? Wq : Wv;
    int idx = blockIdx.x * 256 + threadIdx.x;      // 0 .. C*H-1
    int c = idx >> 7;
    int h = idx & 127;
    Wt[w * (Cn * Hn) + h * Cn + c] = (f16)W[idx];  // row n = w*128+h, len Cn
}

// ---------------------------------------------------------------------------
// Kernel 2: fused QKV projection.  [k|q|v] = X @ [Wk|Wq|Wv] + bias, k *= 1/32.
// grid = Mn/32 = 256 blocks, 512 threads (8 waves). BM=32, BN=384, BK=64.
// Wave w: full 32 m-rows x 48 n-cols (2 m-tiles x 3 n-tiles). X read ONCE.
// ---------------------------------------------------------------------------
__global__ __launch_bounds__(512) void qkv_gemm(const float* __restrict__ X,
                                                const f16* __restrict__ Wt,
                                                const float* __restrict__ bk,
                                                const float* __restrict__ bq,
                                                const float* __restrict__ bv,
                                                f16* __restrict__ proj) {
    __shared__ __align__(16) f16 As[32 * 72];
    __shared__ __align__(16) f16 Bs[384 * 72];

    const int tid  = threadIdx.x;
    const int r0   = blockIdx.x * 32;
    const int lane = tid & 63, wid = tid >> 6;
    const int quad = lane >> 4, l16 = lane & 15;
    const int nbase = wid * 48;

    f32x4 acc[2][3] = {};

    for (int k0 = 0; k0 < Cn; k0 += 64) {
        // A: 32 rows x 64 k fp32->f16: 512 float4, one per thread
        {
            int row = tid >> 4, c4 = tid & 15;
            float4 x = *(const float4*)(X + (r0 + row) * Cn + k0 + c4 * 4);
            f16x4 v = { (f16)x.x, (f16)x.y, (f16)x.z, (f16)x.w };
            *(f16x4*)(&As[row * 72 + c4 * 4]) = v;
        }
        // B: 384 rows x 64 k f16 = 3072 chunks of 8, SIX per thread (512 thr)
        for (int i = 0; i < 6; i++) {
            int ci = tid + 512 * i;
            int row = ci >> 3, cc = ci & 7;
            *(f16x8*)(&Bs[row * 72 + cc * 8]) =
                *(const f16x8*)(Wt + row * Cn + k0 + cc * 8);
        }
        __syncthreads();
        for (int ks = 0; ks < 2; ks++) {
            int kk = ks * 32;
            f16x8 af[2], bf[3];
            for (int mt = 0; mt < 2; mt++)
                af[mt] = *(const f16x8*)(&As[(mt * 16 + l16) * 72 + kk + quad * 8]);
            for (int nt = 0; nt < 3; nt++)
                bf[nt] = *(const f16x8*)(&Bs[(nbase + nt * 16 + l16) * 72 + kk + quad * 8]);
            for (int mt = 0; mt < 2; mt++)
                for (int nt = 0; nt < 3; nt++)
                    acc[mt][nt] = __builtin_amdgcn_mfma_f32_16x16x32_f16(
                        af[mt], bf[nt], acc[mt][nt], 0, 0, 0);
        }
        __syncthreads();
    }

    for (int nt = 0; nt < 3; nt++) {
        int n0 = nbase + nt * 16;           // tile-uniform; never straddles 128
        int wsel = n0 >> 7;
        int col = (n0 & 127) + l16;
        const float* bias = (wsel == 0) ? bk : (wsel == 1) ? bq : bv;
        float bval = bias[col];
        float scale = (wsel == 0) ? 0.03125f : 1.0f;   // fold C^-0.5 into k
        f16* P = proj + wsel * (Mn * Hn);
        for (int mt = 0; mt < 2; mt++)
            for (int r = 0; r < 4; r++) {
                int m = r0 + mt * 16 + quad * 4 + r;
                P[m * Hn + col] = (f16)((acc[mt][nt][r] + bval) * scale);
            }
    }
}

// ---------------------------------------------------------------------------
// Kernel 3: transpose v: proj_v [b][s][h] -> vT [b][h][s] (64x64 LDS tiles).
// grid = (Tn/64, Hn/64, Bn) = (32,2,4), 256 threads.
// ---------------------------------------------------------------------------
__global__ __launch_bounds__(256) void vt_transpose(const f16* __restrict__ pv,
                                                    f16* __restrict__ vT) {
    __shared__ __align__(16) f16 T[64 * 72];
    const int tid = threadIdx.x;
    const int s0 = blockIdx.x * 64, h0 = blockIdx.y * 64, b = blockIdx.z;
    for (int i = 0; i < 2; i++) {
        int ci = tid + 256 * i;
        int row = ci >> 3, hc = ci & 7;
        *(f16x8*)(&T[row * 72 + hc * 8]) =
            *(const f16x8*)(pv + (b * Tn + s0 + row) * Hn + h0 + hc * 8);
    }
    __syncthreads();
    for (int i = 0; i < 2; i++) {
        int ci = tid + 256 * i;
        int h = ci >> 3, sc = ci & 7;
        f16x8 v;
        for (int j = 0; j < 8; j++) v[j] = T[(sc * 8 + j) * 72 + h];
        *(f16x8*)(&vT[(b * Hn + h0 + h) * Tn + s0 + sc * 8]) = v;
    }
}

// ---------------------------------------------------------------------------
// Kernel 4: flash attention over an s-chunk, register-resident softmax.
// grid = (Tn/64, SCHUNKS, Bn) = (32,4,4) = 512 blocks, 256 threads (4 waves).
// Wave = one 16-row t-tile. Computes S^T = q k^T (t in l16, s in quad*4+reg);
// P stays in registers as the K=16 MFMA B-operand. Partials (O^T,m,l) -> ws.
// ---------------------------------------------------------------------------
__global__ __launch_bounds__(256) void attn_kernel(const f16* __restrict__ pk,
                                                   const f16* __restrict__ pq,
                                                   const f16* __restrict__ vT,
                                                   float* __restrict__ pO,
                                                   float* __restrict__ pm,
                                                   float* __restrict__ pl) {
    __shared__ __align__(16) char smem[36864];
    f16* Bq = (f16*)smem;                 // [64][136] q rows (s-major)
    f16* Vt = (f16*)(smem + 17408);       // [128][72]  vT tile (h-major)

    const int tid  = threadIdx.x;
    const int tblk = blockIdx.x, c = blockIdx.y, b = blockIdx.z;
    const int t0   = tblk * 64;
    const int lane = tid & 63, wid = tid >> 6;
    const int quad = lane >> 4, l16 = lane & 15;
    const int tg   = t0 + wid * 16 + l16;          // this lane's t (as B-col)

    const f16* kp = pk + b * Tn * Hn;
    const f16* qp = pq + b * Tn * Hn;
    const f16* vp = vT + b * Hn * Tn;

    // hoist k fragments for the wave's t-tile: B[n=t(l16)][k=h], 4 K32-steps
    f16x8 kfr[4];
    for (int ks = 0; ks < 4; ks++)
        kfr[ks] = *(const f16x8*)(kp + tg * Hn + ks * 32 + quad * 8);

    float m_i = -3e38f, l_i = 0.0f;
    f32x4 accO[8] = {};

    for (int si = 0; si < SCHUNK / 64; si++) {
        const int s0 = c * SCHUNK + si * 64;
        // stage q rows: 64 s x 128 h, 1024 chunks, 4/thread
        for (int i = 0; i < 4; i++) {
            int ci = tid + 256 * i;
            int row = ci >> 4, hc = ci & 15;
            *(f16x8*)(&Bq[row * 136 + hc * 8]) =
                *(const f16x8*)(qp + (s0 + row) * Hn + hc * 8);
        }
        // stage vT tile: 128 h x 64 s, 1024 chunks, 4/thread
        for (int i = 0; i < 4; i++) {
            int ci = tid + 256 * i;
            int h = ci >> 3, sc = ci & 7;
            *(f16x8*)(&Vt[h * 72 + sc * 8]) =
                *(const f16x8*)(vp + h * Tn + s0 + sc * 8);
        }
        __syncthreads();

        // S^T tiles: A = q rows (m=s), B = k frags (n=t). 4 s-tiles x 4 K-steps
        f32x4 accS[4] = {};
        for (int ks = 0; ks < 4; ks++) {
            int kk = ks * 32;
            for (int st = 0; st < 4; st++) {
                f16x8 af = *(const f16x8*)(&Bq[(st * 16 + l16) * 136 + kk + quad * 8]);
                accS[st] = __builtin_amdgcn_mfma_f32_16x16x32_f16(af, kfr[ks], accS[st], 0, 0, 0);
            }
        }

        // online softmax fully in registers: row = t = l16; s spread over
        // quad (xor16,32) x reg x s-tile.
        float mloc = -3e38f;
        for (int st = 0; st < 4; st++)
            for (int r = 0; r < 4; r++) mloc = fmaxf(mloc, accS[st][r]);
        mloc = fmaxf(mloc, __shfl_xor(mloc, 16));
        mloc = fmaxf(mloc, __shfl_xor(mloc, 32));
        float mnew = fmaxf(m_i, mloc);
        float alpha = __expf(m_i - mnew);
        m_i = mnew;

        f16x4 pf[4];
        float psum = 0.0f;
        for (int st = 0; st < 4; st++) {
            f32x4 p;
            for (int r = 0; r < 4; r++) {
                p[r] = __expf(accS[st][r] - mnew);
                psum += p[r];
            }
            pf[st] = { (f16)p[0], (f16)p[1], (f16)p[2], (f16)p[3] };
        }
        psum += __shfl_xor(psum, 16);
        psum += __shfl_xor(psum, 32);
        l_i = l_i * alpha + psum;

        for (int ht = 0; ht < 8; ht++)
            for (int r = 0; r < 4; r++) accO[ht][r] *= alpha;

        // O^T += Vt . P  (K=16). A = vT rows (m=h), B = P in regs (n=t).
        for (int st = 0; st < 4; st++) {
            for (int ht = 0; ht < 8; ht++) {
                f16x4 av = *(const f16x4*)(&Vt[(ht * 16 + l16) * 72 + st * 16 + quad * 4]);
                accO[ht] = __builtin_amdgcn_mfma_f32_16x16x16f16(av, pf[st], accO[ht], 0, 0, 0);
            }
        }
        __syncthreads();   // before next staging overwrites Bq/Vt
    }

    // epilogue: transpose O^T (h=quad*4+reg, t=l16) -> [t][h] via LDS, store
    float* ep = (float*)smem + wid * 2048;     // 16t x 128h per wave (8 KB)
    for (int ht = 0; ht < 8; ht++)
        for (int r = 0; r < 4; r++)
            ep[(ht * 16 + quad * 4 + r) * 16 + l16] = accO[ht][r];
    __syncthreads();
    {
        int t = lane >> 2, hq = lane & 3;
        int tgl = t0 + wid * 16 + t;
        float* dst = pO + ((size_t)(c * Bn + b) * Tn + tgl) * Hn + hq * 32;
        for (int j = 0; j < 8; j++) {
            float4 v = { ep[(hq * 32 + j * 4 + 0) * 16 + t],
                         ep[(hq * 32 + j * 4 + 1) * 16 + t],
                         ep[(hq * 32 + j * 4 + 2) * 16 + t],
                         ep[(hq * 32 + j * 4 + 3) * 16 + t] };
            *(float4*)(dst + j * 4) = v;
        }
    }
    if (quad == 0) {
        pm[(c * Bn + b) * Tn + t0 + wid * 16 + l16] = m_i;
        pl[(c * Bn + b) * Tn + t0 + wid * 16 + l16] = l_i;
    }
}

// ---------------------------------------------------------------------------
// Kernel 5: merge SCHUNKS partials. thread -> (b,t, 32 h's). Coalesced.
// grid = 128 blocks x 256 threads.
// ---------------------------------------------------------------------------
__global__ __launch_bounds__(256) void merge_kernel(const float* __restrict__ pO,
                                                    const float* __restrict__ pm,
                                                    const float* __restrict__ pl,
                                                    float* __restrict__ out) {
    int gid = blockIdx.x * 256 + threadIdx.x;   // 0..32767
    int tg = gid >> 2;                          // b*Tn + t  (0..8191)
    int hq = gid & 3;
    float mc[SCHUNKS], lc[SCHUNKS];
    float M = -3e38f;
    for (int cI = 0; cI < SCHUNKS; cI++) {
        mc[cI] = pm[cI * (Bn * Tn) + tg];
        lc[cI] = pl[cI * (Bn * Tn) + tg];
        M = fmaxf(M, mc[cI]);
    }
    float L = 0.0f, wc[SCHUNKS];
    for (int cI = 0; cI < SCHUNKS; cI++) {
        wc[cI] = __expf(mc[cI] - M);
        L += wc[cI] * lc[cI];
    }
    float inv = 1.0f / L;
    float4 o[8] = {};
    for (int cI = 0; cI < SCHUNKS; cI++) {
        const float* src = pO + ((size_t)cI * Bn * Tn + tg) * Hn + hq * 32;
        float w = wc[cI];
        for (int j = 0; j < 8; j++) {
            float4 v = *(const float4*)(src + j * 4);
            o[j].x += w * v.x; o[j].y += w * v.y; o[j].z += w * v.z; o[j].w += w * v.w;
        }
    }
    float* dst = out + (size_t)tg * Hn + hq * 32;
    for (int j = 0; j < 8; j++) {
        float4 v = { o[j].x * inv, o[j].y * inv, o[j].z * inv, o[j].w * inv };
        *(float4*)(dst + j * 4) = v;
    }
}

extern "C" void kernel_launch(void* const* d_in, const int* in_sizes, int n_in,
                              void* d_out, int out_size, void* d_ws, size_t ws_size,
                              hipStream_t stream) {
    const float* X  = (const float*)d_in[0];
    const float* Wk = (const float*)d_in[1];
    const float* bk = (const float*)d_in[2];
    const float* Wq = (const float*)d_in[3];
    const float* bq = (const float*)d_in[4];
    const float* Wv = (const float*)d_in[5];
    const float* bv = (const float*)d_in[6];
    float* out = (float*)d_out;

    // ws layout (bytes):
    //   Wt   [384][1024] f16        @ 0          (786,432)
    //   proj [3][8192][128] f16     @ 786,432    (6,291,456)
    //   vT   [4][128][2048] f16     @ 7,077,888  (2,097,152)
    //   pO   [4][4][2048][128] f32  @ 9,175,040  (16,777,216)
    //   pm   [4][4][2048] f32       @ 25,952,256 (131,072)
    //   pl   [4][4][2048] f32       @ 26,083,328 (131,072)   total ~26.2 MB
    char* base = (char*)d_ws;
    f16*   Wt   = (f16*)(base);
    f16*   proj = (f16*)(base + 786432);
    f16*   pk   = proj;
    f16*   pq   = proj + Mn * Hn;
    f16*   pv   = proj + 2 * Mn * Hn;
    f16*   vT   = (f16*)(base + 7077888);
    float* pO   = (float*)(base + 9175040);
    float* pm   = (float*)(base + 25952256);
    float* pl   = (float*)(base + 26083328);

    prep_w<<<dim3(512, 3), 256, 0, stream>>>(Wk, Wq, Wv, Wt);
    qkv_gemm<<<dim3(Mn / 32), 512, 0, stream>>>(X, Wt, bk, bq, bv, proj);
    vt_transpose<<<dim3(Tn / 64, Hn / 64, Bn), 256, 0, stream>>>(pv, vT);
    attn_kernel<<<dim3(Tn / 64, SCHUNKS, Bn), 256, 0, stream>>>(pk, pq, vT, pO, pm, pl);
    merge_kernel<<<dim3(128), 256, 0, stream>>>(pO, pm, pl, out);
}

// Round 5
// 136.381 us; speedup vs baseline: 1.3373x; 1.0722x over previous
//
#include <hip/hip_runtime.h>
#include <hip/hip_bf16.h>

// Problem constants: B=4, T=2048, C(n_embd)=1024, H(head)=128
#define Bn 4
#define Tn 2048
#define Cn 1024
#define Hn 128
#define Mn (Bn*Tn)   // 8192 rows of X
#define SCHUNKS 8    // s-split across blocks in attention
#define SCHUNK  (Tn/SCHUNKS)   // 256

typedef _Float16 f16;
typedef __attribute__((ext_vector_type(4))) _Float16 f16x4;  // 2 VGPRs
typedef __attribute__((ext_vector_type(8))) _Float16 f16x8;  // 4 VGPRs
typedef __attribute__((ext_vector_type(4))) float f32x4;

// ---------------------------------------------------------------------------
// Kernel 1: transpose + convert weights [C][H] fp32 -> fused [3*H][C] fp16.
// ---------------------------------------------------------------------------
__global__ void prep_w(const float* __restrict__ Wk, const float* __restrict__ Wq,
                       const float* __restrict__ Wv, f16* __restrict__ Wt) {
    const int w = blockIdx.y;
    const float* W = (w == 0) ? Wk : (w == 1) ? Wq : Wv;
    int idx = blockIdx.x * 256 + threadIdx.x;      // 0 .. C*H-1
    int c = idx >> 7;
    int h = idx & 127;
    Wt[w * (Cn * Hn) + h * Cn + c] = (f16)W[idx];  // row n = w*128+h, len Cn
}

// ---------------------------------------------------------------------------
// Kernel 2: fused QKV projection.  [k|q|v] = X @ [Wk|Wq|Wv] + bias, k *= 1/32.
// grid = Mn/32 = 256 blocks, 512 threads (8 waves). BM=32, BN=384, BK=64.
// ---------------------------------------------------------------------------
__global__ __launch_bounds__(512) void qkv_gemm(const float* __restrict__ X,
                                                const f16* __restrict__ Wt,
                                                const float* __restrict__ bk,
                                                const float* __restrict__ bq,
                                                const float* __restrict__ bv,
                                                f16* __restrict__ proj) {
    __shared__ __align__(16) f16 As[32 * 72];
    __shared__ __align__(16) f16 Bs[384 * 72];

    const int tid  = threadIdx.x;
    const int r0   = blockIdx.x * 32;
    const int lane = tid & 63, wid = tid >> 6;
    const int quad = lane >> 4, l16 = lane & 15;
    const int nbase = wid * 48;

    f32x4 acc[2][3] = {};

    for (int k0 = 0; k0 < Cn; k0 += 64) {
        {
            int row = tid >> 4, c4 = tid & 15;
            float4 x = *(const float4*)(X + (r0 + row) * Cn + k0 + c4 * 4);
            f16x4 v = { (f16)x.x, (f16)x.y, (f16)x.z, (f16)x.w };
            *(f16x4*)(&As[row * 72 + c4 * 4]) = v;
        }
        for (int i = 0; i < 6; i++) {
            int ci = tid + 512 * i;
            int row = ci >> 3, cc = ci & 7;
            *(f16x8*)(&Bs[row * 72 + cc * 8]) =
                *(const f16x8*)(Wt + row * Cn + k0 + cc * 8);
        }
        __syncthreads();
        for (int ks = 0; ks < 2; ks++) {
            int kk = ks * 32;
            f16x8 af[2], bf[3];
            for (int mt = 0; mt < 2; mt++)
                af[mt] = *(const f16x8*)(&As[(mt * 16 + l16) * 72 + kk + quad * 8]);
            for (int nt = 0; nt < 3; nt++)
                bf[nt] = *(const f16x8*)(&Bs[(nbase + nt * 16 + l16) * 72 + kk + quad * 8]);
            for (int mt = 0; mt < 2; mt++)
                for (int nt = 0; nt < 3; nt++)
                    acc[mt][nt] = __builtin_amdgcn_mfma_f32_16x16x32_f16(
                        af[mt], bf[nt], acc[mt][nt], 0, 0, 0);
        }
        __syncthreads();
    }

    for (int nt = 0; nt < 3; nt++) {
        int n0 = nbase + nt * 16;
        int wsel = n0 >> 7;
        int col = (n0 & 127) + l16;
        const float* bias = (wsel == 0) ? bk : (wsel == 1) ? bq : bv;
        float bval = bias[col];
        float scale = (wsel == 0) ? 0.03125f : 1.0f;   // fold C^-0.5 into k
        f16* P = proj + wsel * (Mn * Hn);
        for (int mt = 0; mt < 2; mt++)
            for (int r = 0; r < 4; r++) {
                int m = r0 + mt * 16 + quad * 4 + r;
                P[m * Hn + col] = (f16)((acc[mt][nt][r] + bval) * scale);
            }
    }
}

// ---------------------------------------------------------------------------
// Kernel 3: transpose v: proj_v [b][s][h] -> vT [b][h][s] (64x64 LDS tiles).
// ---------------------------------------------------------------------------
__global__ __launch_bounds__(256) void vt_transpose(const f16* __restrict__ pv,
                                                    f16* __restrict__ vT) {
    __shared__ __align__(16) f16 T[64 * 72];
    const int tid = threadIdx.x;
    const int s0 = blockIdx.x * 64, h0 = blockIdx.y * 64, b = blockIdx.z;
    for (int i = 0; i < 2; i++) {
        int ci = tid + 256 * i;
        int row = ci >> 3, hc = ci & 7;
        *(f16x8*)(&T[row * 72 + hc * 8]) =
            *(const f16x8*)(pv + (b * Tn + s0 + row) * Hn + h0 + hc * 8);
    }
    __syncthreads();
    for (int i = 0; i < 2; i++) {
        int ci = tid + 256 * i;
        int h = ci >> 3, sc = ci & 7;
        f16x8 v;
        for (int j = 0; j < 8; j++) v[j] = T[(sc * 8 + j) * 72 + h];
        *(f16x8*)(&vT[(b * Hn + h0 + h) * Tn + s0 + sc * 8]) = v;
    }
}

// ---------------------------------------------------------------------------
// Kernel 4: flash attention over an s-chunk. 128 t per block (32 t/wave, two
// 16-t tiles). Bq/Vt fragments are t-independent -> read once, used twice.
// grid = (Tn/128, SCHUNKS, Bn) = (16,8,4) = 512 blocks, 256 threads (4 waves).
// S^T = q k^T (t in l16, s in quad*4+reg); P stays in registers as the K=16
// MFMA B-operand. Partials: O^T -> f16 pO, (m,l) -> f32.
// ---------------------------------------------------------------------------
__global__ __launch_bounds__(256, 2) void attn_kernel(const f16* __restrict__ pk,
                                                      const f16* __restrict__ pq,
                                                      const f16* __restrict__ vT,
                                                      f16* __restrict__ pO,
                                                      float* __restrict__ pm,
                                                      float* __restrict__ pl) {
    __shared__ __align__(16) char smem[36864];
    f16* Bq = (f16*)smem;                 // [64][136] q rows (s-major)
    f16* Vt = (f16*)(smem + 17408);       // [128][72]  vT tile (h-major)

    const int tid  = threadIdx.x;
    const int tblk = blockIdx.x, c = blockIdx.y, b = blockIdx.z;
    const int t0   = tblk * 128;
    const int lane = tid & 63, wid = tid >> 6;
    const int quad = lane >> 4, l16 = lane & 15;
    const int tw   = t0 + wid * 32;                // wave's 32-t base

    const f16* kp = pk + b * Tn * Hn;
    const f16* qp = pq + b * Tn * Hn;
    const f16* vp = vT + b * Hn * Tn;

    // hoist k fragments: 2 t-tiles x 4 K32-steps, B[n=t(l16)][k=h]
    f16x8 kfr[2][4];
    for (int tt = 0; tt < 2; tt++)
        for (int ks = 0; ks < 4; ks++)
            kfr[tt][ks] = *(const f16x8*)(kp + (tw + tt * 16 + l16) * Hn + ks * 32 + quad * 8);

    float m_i[2] = { -3e38f, -3e38f }, l_i[2] = { 0.0f, 0.0f };
    f32x4 accO[2][8] = {};

    for (int si = 0; si < SCHUNK / 64; si++) {
        const int s0 = c * SCHUNK + si * 64;
        // stage q rows: 64 s x 128 h, 1024 chunks, 4/thread
        for (int i = 0; i < 4; i++) {
            int ci = tid + 256 * i;
            int row = ci >> 4, hc = ci & 15;
            *(f16x8*)(&Bq[row * 136 + hc * 8]) =
                *(const f16x8*)(qp + (s0 + row) * Hn + hc * 8);
        }
        // stage vT tile: 128 h x 64 s, 1024 chunks, 4/thread
        for (int i = 0; i < 4; i++) {
            int ci = tid + 256 * i;
            int h = ci >> 3, sc = ci & 7;
            *(f16x8*)(&Vt[h * 72 + sc * 8]) =
                *(const f16x8*)(vp + h * Tn + s0 + sc * 8);
        }
        __syncthreads();

        // S^T tiles: A = q rows (m=s), B = k frags (n=t). af shared across tt.
        f32x4 accS[2][4] = {};
        for (int ks = 0; ks < 4; ks++) {
            int kk = ks * 32;
            for (int st = 0; st < 4; st++) {
                f16x8 af = *(const f16x8*)(&Bq[(st * 16 + l16) * 136 + kk + quad * 8]);
                accS[0][st] = __builtin_amdgcn_mfma_f32_16x16x32_f16(af, kfr[0][ks], accS[0][st], 0, 0, 0);
                accS[1][st] = __builtin_amdgcn_mfma_f32_16x16x32_f16(af, kfr[1][ks], accS[1][st], 0, 0, 0);
            }
        }

        // online softmax in registers: row = t = l16; s over quad x reg x st.
        f16x4 pf[2][4];
        for (int tt = 0; tt < 2; tt++) {
            float mloc = -3e38f;
            for (int st = 0; st < 4; st++)
                for (int r = 0; r < 4; r++) mloc = fmaxf(mloc, accS[tt][st][r]);
            mloc = fmaxf(mloc, __shfl_xor(mloc, 16));
            mloc = fmaxf(mloc, __shfl_xor(mloc, 32));
            float mnew = fmaxf(m_i[tt], mloc);
            float alpha = __expf(m_i[tt] - mnew);
            m_i[tt] = mnew;
            float psum = 0.0f;
            for (int st = 0; st < 4; st++) {
                f32x4 p;
                for (int r = 0; r < 4; r++) {
                    p[r] = __expf(accS[tt][st][r] - mnew);
                    psum += p[r];
                }
                pf[tt][st] = { (f16)p[0], (f16)p[1], (f16)p[2], (f16)p[3] };
            }
            psum += __shfl_xor(psum, 16);
            psum += __shfl_xor(psum, 32);
            l_i[tt] = l_i[tt] * alpha + psum;
            for (int ht = 0; ht < 8; ht++)
                for (int r = 0; r < 4; r++) accO[tt][ht][r] *= alpha;
        }

        // O^T += Vt . P  (K=16). av shared across tt.
        for (int st = 0; st < 4; st++) {
            for (int ht = 0; ht < 8; ht++) {
                f16x4 av = *(const f16x4*)(&Vt[(ht * 16 + l16) * 72 + st * 16 + quad * 4]);
                accO[0][ht] = __builtin_amdgcn_mfma_f32_16x16x16f16(av, pf[0][st], accO[0][ht], 0, 0, 0);
                accO[1][ht] = __builtin_amdgcn_mfma_f32_16x16x16f16(av, pf[1][st], accO[1][ht], 0, 0, 0);
            }
        }
        __syncthreads();   // before next staging overwrites Bq/Vt
    }

    // epilogue: per t-tile, transpose O^T (h=quad*4+reg, t=l16) via LDS,
    // store f16 partials. Uniform control flow -> barriers are safe.
    for (int tt = 0; tt < 2; tt++) {
        __syncthreads();
        float* ep = (float*)smem + wid * 2048;     // 16t x 128h per wave (8 KB)
        for (int ht = 0; ht < 8; ht++)
            for (int r = 0; r < 4; r++)
                ep[(ht * 16 + quad * 4 + r) * 16 + l16] = accO[tt][ht][r];
        __syncthreads();
        {
            int t = lane >> 2, hq = lane & 3;
            int tgl = tw + tt * 16 + t;
            f16* dst = pO + ((size_t)(c * Bn + b) * Tn + tgl) * Hn + hq * 32;
            for (int g = 0; g < 4; g++) {          // 4 x f16x8 = 32 h
                f16x8 v;
                for (int j = 0; j < 8; j++)
                    v[j] = (f16)ep[(hq * 32 + g * 8 + j) * 16 + t];
                *(f16x8*)(dst + g * 8) = v;
            }
        }
        if (quad == 0) {
            pm[(c * Bn + b) * Tn + tw + tt * 16 + l16] = m_i[tt];
            pl[(c * Bn + b) * Tn + tw + tt * 16 + l16] = l_i[tt];
        }
    }
}

// ---------------------------------------------------------------------------
// Kernel 5: merge SCHUNKS partials. thread -> (b,t, 32 h's). Coalesced.
// grid = 128 blocks x 256 threads.
// ---------------------------------------------------------------------------
__global__ __launch_bounds__(256) void merge_kernel(const f16* __restrict__ pO,
                                                    const float* __restrict__ pm,
                                                    const float* __restrict__ pl,
                                                    float* __restrict__ out) {
    int gid = blockIdx.x * 256 + threadIdx.x;   // 0..32767
    int tg = gid >> 2;                          // b*Tn + t  (0..8191)
    int hq = gid & 3;
    float mc[SCHUNKS], lc[SCHUNKS];
    float M = -3e38f;
    for (int cI = 0; cI < SCHUNKS; cI++) {
        mc[cI] = pm[cI * (Bn * Tn) + tg];
        lc[cI] = pl[cI * (Bn * Tn) + tg];
        M = fmaxf(M, mc[cI]);
    }
    float L = 0.0f, wc[SCHUNKS];
    for (int cI = 0; cI < SCHUNKS; cI++) {
        wc[cI] = __expf(mc[cI] - M);
        L += wc[cI] * lc[cI];
    }
    float inv = 1.0f / L;
    float o[32] = {};
    for (int cI = 0; cI < SCHUNKS; cI++) {
        const f16* src = pO + ((size_t)cI * Bn * Tn + tg) * Hn + hq * 32;
        float w = wc[cI];
        for (int g = 0; g < 4; g++) {
            f16x8 v = *(const f16x8*)(src + g * 8);
            for (int j = 0; j < 8; j++) o[g * 8 + j] += w * (float)v[j];
        }
    }
    float* dst = out + (size_t)tg * Hn + hq * 32;
    for (int g = 0; g < 8; g++) {
        float4 v = { o[g*4+0] * inv, o[g*4+1] * inv, o[g*4+2] * inv, o[g*4+3] * inv };
        *(float4*)(dst + g * 4) = v;
    }
}

extern "C" void kernel_launch(void* const* d_in, const int* in_sizes, int n_in,
                              void* d_out, int out_size, void* d_ws, size_t ws_size,
                              hipStream_t stream) {
    const float* X  = (const float*)d_in[0];
    const float* Wk = (const float*)d_in[1];
    const float* bk = (const float*)d_in[2];
    const float* Wq = (const float*)d_in[3];
    const float* bq = (const float*)d_in[4];
    const float* Wv = (const float*)d_in[5];
    const float* bv = (const float*)d_in[6];
    float* out = (float*)d_out;

    // ws layout (bytes):
    //   Wt   [384][1024] f16        @ 0          (786,432)
    //   proj [3][8192][128] f16     @ 786,432    (6,291,456)
    //   vT   [4][128][2048] f16     @ 7,077,888  (2,097,152)
    //   pO   [8][4][2048][128] f16  @ 9,175,040  (16,777,216)
    //   pm   [8][4][2048] f32       @ 25,952,256 (262,144)
    //   pl   [8][4][2048] f32       @ 26,214,400 (262,144)   total ~26.5 MB
    char* base = (char*)d_ws;
    f16*   Wt   = (f16*)(base);
    f16*   proj = (f16*)(base + 786432);
    f16*   pk   = proj;
    f16*   pq   = proj + Mn * Hn;
    f16*   pv   = proj + 2 * Mn * Hn;
    f16*   vT   = (f16*)(base + 7077888);
    f16*   pO   = (f16*)(base + 9175040);
    float* pm   = (float*)(base + 25952256);
    float* pl   = (float*)(base + 26214400);

    prep_w<<<dim3(512, 3), 256, 0, stream>>>(Wk, Wq, Wv, Wt);
    qkv_gemm<<<dim3(Mn / 32), 512, 0, stream>>>(X, Wt, bk, bq, bv, proj);
    vt_transpose<<<dim3(Tn / 64, Hn / 64, Bn), 256, 0, stream>>>(pv, vT);
    attn_kernel<<<dim3(Tn / 128, SCHUNKS, Bn), 256, 0, stream>>>(pk, pq, vT, pO, pm, pl);
    merge_kernel<<<dim3(128), 256, 0, stream>>>(pO, pm, pl, out);
}

// Round 6
// 130.964 us; speedup vs baseline: 1.3926x; 1.0414x over previous
//
#include <hip/hip_runtime.h>
#include <hip/hip_bf16.h>

// Problem constants: B=4, T=2048, C(n_embd)=1024, H(head)=128
#define Bn 4
#define Tn 2048
#define Cn 1024
#define Hn 128
#define Mn (Bn*Tn)   // 8192 rows of X
#define SCHUNKS 8    // s-split across blocks in attention
#define SCHUNK  (Tn/SCHUNKS)   // 256

typedef _Float16 f16;
typedef __attribute__((ext_vector_type(4))) _Float16 f16x4;  // 2 VGPRs
typedef __attribute__((ext_vector_type(8))) _Float16 f16x8;  // 4 VGPRs
typedef __attribute__((ext_vector_type(4))) float f32x4;

// ---------------------------------------------------------------------------
// Kernel 1: transpose + convert weights [C][H] fp32 -> fused [3*H][C] fp16.
// ---------------------------------------------------------------------------
__global__ void prep_w(const float* __restrict__ Wk, const float* __restrict__ Wq,
                       const float* __restrict__ Wv, f16* __restrict__ Wt) {
    const int w = blockIdx.y;
    const float* W = (w == 0) ? Wk : (w == 1) ? Wq : Wv;
    int idx = blockIdx.x * 256 + threadIdx.x;      // 0 .. C*H-1
    int c = idx >> 7;
    int h = idx & 127;
    Wt[w * (Cn * Hn) + h * Cn + c] = (f16)W[idx];  // row n = w*128+h, len Cn
}

// ---------------------------------------------------------------------------
// Kernel 2: fused QKV projection.  [k|q|v] = X @ [Wk|Wq|Wv] + bias, k *= 1/32.
// grid = (Mn/64, 2) = 256 blocks, 512 threads (8 waves). BM=64, BN=192 (n-split
// halves Wt re-reads: 98 MB vs 196 MB), BK=64. Wave grid 2m x 4n.
// Epilogue routes through LDS: k/q stored row-major f16x8; v stored DIRECTLY
// transposed into vT[b][h][s] (vt_transpose kernel eliminated).
// ---------------------------------------------------------------------------
__global__ __launch_bounds__(512) void qkv_gemm(const float* __restrict__ X,
                                                const f16* __restrict__ Wt,
                                                const float* __restrict__ bk,
                                                const float* __restrict__ bq,
                                                const float* __restrict__ bv,
                                                f16* __restrict__ pk,
                                                f16* __restrict__ pq,
                                                f16* __restrict__ vT) {
    __shared__ __align__(16) char smem[36864];
    f16* As = (f16*)smem;                  // [64][72]
    f16* Bs = (f16*)(smem + 9216);         // [192][72]

    const int tid  = threadIdx.x;
    const int r0   = blockIdx.x * 64;
    const int ns   = blockIdx.y;           // 0: n 0..191, 1: n 192..383
    const int lane = tid & 63, wid = tid >> 6;
    const int quad = lane >> 4, l16 = lane & 15;
    const int wm = wid >> 2, wn = wid & 3;

    f32x4 acc[2][3] = {};

    for (int k0 = 0; k0 < Cn; k0 += 64) {
        // A: 64 rows x 64 k fp32->f16: 1024 float4, 2/thread
        for (int i = 0; i < 2; i++) {
            int ci = tid + 512 * i;
            int row = ci >> 4, c4 = ci & 15;
            float4 x = *(const float4*)(X + (r0 + row) * Cn + k0 + c4 * 4);
            f16x4 v = { (f16)x.x, (f16)x.y, (f16)x.z, (f16)x.w };
            *(f16x4*)(&As[row * 72 + c4 * 4]) = v;
        }
        // B: 192 rows x 8 chunks = 1536, 3/thread
        for (int i = 0; i < 3; i++) {
            int ci = tid + 512 * i;
            int row = ci >> 3, cc = ci & 7;
            *(f16x8*)(&Bs[row * 72 + cc * 8]) =
                *(const f16x8*)(Wt + (ns * 192 + row) * Cn + k0 + cc * 8);
        }
        __syncthreads();
        for (int ks = 0; ks < 2; ks++) {
            int kk = ks * 32;
            f16x8 af[2], bf[3];
            for (int mt = 0; mt < 2; mt++)
                af[mt] = *(const f16x8*)(&As[(wm * 32 + mt * 16 + l16) * 72 + kk + quad * 8]);
            for (int nt = 0; nt < 3; nt++)
                bf[nt] = *(const f16x8*)(&Bs[(wn * 48 + nt * 16 + l16) * 72 + kk + quad * 8]);
            for (int mt = 0; mt < 2; mt++)
                for (int nt = 0; nt < 3; nt++)
                    acc[mt][nt] = __builtin_amdgcn_mfma_f32_16x16x32_f16(
                        af[mt], bf[nt], acc[mt][nt], 0, 0, 0);
        }
        __syncthreads();
    }

    // ---- epilogue via LDS: E [64 rows][200] f16 (reuses staging smem) ----
    f16* E = (f16*)smem;
    for (int nt = 0; nt < 3; nt++) {
        int n0 = ns * 192 + wn * 48 + nt * 16;
        int wsel = n0 >> 7;
        int col = (n0 & 127) + l16;
        const float* bias = (wsel == 0) ? bk : (wsel == 1) ? bq : bv;
        float bval = bias[col];
        float scale = (wsel == 0) ? 0.03125f : 1.0f;   // fold C^-0.5 into k
        for (int mt = 0; mt < 2; mt++)
            for (int r = 0; r < 4; r++) {
                int mrow = wm * 32 + mt * 16 + quad * 4 + r;
                E[mrow * 200 + wn * 48 + nt * 16 + l16] =
                    (f16)((acc[mt][nt][r] + bval) * scale);
            }
    }
    __syncthreads();

    if (ns == 0) {
        // all 192 cols are k(0..127) | q(0..63): 64 rows x 24 chunks = 1536
        for (int i = 0; i < 3; i++) {
            int ci = tid + 512 * i;
            int row = ci / 24, c = ci % 24;
            f16x8 v = *(const f16x8*)(&E[row * 200 + c * 8]);
            int gn = c * 8;                      // 0..191
            f16* dst = (gn < 128) ? (pk + (r0 + row) * Hn + gn)
                                  : (pq + (r0 + row) * Hn + (gn - 128));
            *(f16x8*)dst = v;
        }
    } else {
        // local cols 0..63 = q(64..127): 64 rows x 8 chunks = 512
        {
            int ci = tid;
            int row = ci >> 3, c = ci & 7;
            f16x8 v = *(const f16x8*)(&E[row * 200 + c * 8]);
            *(f16x8*)(pq + (r0 + row) * Hn + 64 + c * 8) = v;
        }
        // local cols 64..191 = v(0..127) -> vT[b][h][s]: 128 h x 8 s-chunks
        int b = r0 >> 11, sg = r0 & 2047;
        for (int i = 0; i < 2; i++) {
            int ci = tid + 512 * i;
            int h = ci >> 3, sc = ci & 7;
            f16x8 v;
            for (int j = 0; j < 8; j++)
                v[j] = E[(sc * 8 + j) * 200 + 64 + h];
            *(f16x8*)(vT + (b * Hn + h) * Tn + sg + sc * 8) = v;
        }
    }
}

// ---------------------------------------------------------------------------
// Kernel 3: flash attention over an s-chunk. 128 t per block (32 t/wave, two
// 16-t tiles). Bq/Vt fragments are t-independent -> read once, used twice.
// grid = (Tn/128, SCHUNKS, Bn) = (16,8,4) = 512 blocks, 256 threads (4 waves).
// Register prefetch of next iter's q/vT hides global latency behind compute.
// ---------------------------------------------------------------------------
__global__ __launch_bounds__(256, 2) void attn_kernel(const f16* __restrict__ pk,
                                                      const f16* __restrict__ pq,
                                                      const f16* __restrict__ vT,
                                                      f16* __restrict__ pO,
                                                      float* __restrict__ pm,
                                                      float* __restrict__ pl) {
    __shared__ __align__(16) char smem[36864];
    f16* Bq = (f16*)smem;                 // [64][136] q rows (s-major)
    f16* Vt = (f16*)(smem + 17408);       // [128][72]  vT tile (h-major)

    const int tid  = threadIdx.x;
    const int tblk = blockIdx.x, c = blockIdx.y, b = blockIdx.z;
    const int t0   = tblk * 128;
    const int lane = tid & 63, wid = tid >> 6;
    const int quad = lane >> 4, l16 = lane & 15;
    const int tw   = t0 + wid * 32;                // wave's 32-t base

    const f16* kp = pk + b * Tn * Hn;
    const f16* qp = pq + b * Tn * Hn;
    const f16* vp = vT + b * Hn * Tn;

    // hoist k fragments: 2 t-tiles x 4 K32-steps, B[n=t(l16)][k=h]
    f16x8 kfr[2][4];
    for (int tt = 0; tt < 2; tt++)
        for (int ks = 0; ks < 4; ks++)
            kfr[tt][ks] = *(const f16x8*)(kp + (tw + tt * 16 + l16) * Hn + ks * 32 + quad * 8);

    // staging index precompute
    const int qrow = tid >> 4 /* unused placeholder kept simple below */;
    (void)qrow;

    float m_i[2] = { -3e38f, -3e38f }, l_i[2] = { 0.0f, 0.0f };
    f32x4 accO[2][8] = {};

    // prefetch iter 0
    f16x8 qreg[4], vreg[4];
    {
        const int s0 = c * SCHUNK;
        for (int i = 0; i < 4; i++) {
            int ci = tid + 256 * i;
            qreg[i] = *(const f16x8*)(qp + (s0 + (ci >> 4)) * Hn + (ci & 15) * 8);
            vreg[i] = *(const f16x8*)(vp + (ci >> 3) * Tn + s0 + (ci & 7) * 8);
        }
    }

    for (int si = 0; si < SCHUNK / 64; si++) {
        __syncthreads();   // LDS free (previous iter's reads done)
        for (int i = 0; i < 4; i++) {
            int ci = tid + 256 * i;
            *(f16x8*)(&Bq[(ci >> 4) * 136 + (ci & 15) * 8]) = qreg[i];
            *(f16x8*)(&Vt[(ci >> 3) * 72 + (ci & 7) * 8]) = vreg[i];
        }
        __syncthreads();
        if (si + 1 < SCHUNK / 64) {
            const int s1 = c * SCHUNK + (si + 1) * 64;
            for (int i = 0; i < 4; i++) {
                int ci = tid + 256 * i;
                qreg[i] = *(const f16x8*)(qp + (s1 + (ci >> 4)) * Hn + (ci & 15) * 8);
                vreg[i] = *(const f16x8*)(vp + (ci >> 3) * Tn + s1 + (ci & 7) * 8);
            }
        }

        // S^T tiles: A = q rows (m=s), B = k frags (n=t). af shared across tt.
        f32x4 accS[2][4] = {};
        for (int ks = 0; ks < 4; ks++) {
            int kk = ks * 32;
            for (int st = 0; st < 4; st++) {
                f16x8 af = *(const f16x8*)(&Bq[(st * 16 + l16) * 136 + kk + quad * 8]);
                accS[0][st] = __builtin_amdgcn_mfma_f32_16x16x32_f16(af, kfr[0][ks], accS[0][st], 0, 0, 0);
                accS[1][st] = __builtin_amdgcn_mfma_f32_16x16x32_f16(af, kfr[1][ks], accS[1][st], 0, 0, 0);
            }
        }

        // online softmax in registers: row = t = l16; s over quad x reg x st.
        f16x4 pf[2][4];
        for (int tt = 0; tt < 2; tt++) {
            float mloc = -3e38f;
            for (int st = 0; st < 4; st++)
                for (int r = 0; r < 4; r++) mloc = fmaxf(mloc, accS[tt][st][r]);
            mloc = fmaxf(mloc, __shfl_xor(mloc, 16));
            mloc = fmaxf(mloc, __shfl_xor(mloc, 32));
            float mnew = fmaxf(m_i[tt], mloc);
            float alpha = __expf(m_i[tt] - mnew);
            m_i[tt] = mnew;
            float psum = 0.0f;
            for (int st = 0; st < 4; st++) {
                f32x4 p;
                for (int r = 0; r < 4; r++) {
                    p[r] = __expf(accS[tt][st][r] - mnew);
                    psum += p[r];
                }
                pf[tt][st] = { (f16)p[0], (f16)p[1], (f16)p[2], (f16)p[3] };
            }
            psum += __shfl_xor(psum, 16);
            psum += __shfl_xor(psum, 32);
            l_i[tt] = l_i[tt] * alpha + psum;
            for (int ht = 0; ht < 8; ht++)
                for (int r = 0; r < 4; r++) accO[tt][ht][r] *= alpha;
        }

        // O^T += Vt . P  (K=16). av shared across tt.
        for (int st = 0; st < 4; st++) {
            for (int ht = 0; ht < 8; ht++) {
                f16x4 av = *(const f16x4*)(&Vt[(ht * 16 + l16) * 72 + st * 16 + quad * 4]);
                accO[0][ht] = __builtin_amdgcn_mfma_f32_16x16x16f16(av, pf[0][st], accO[0][ht], 0, 0, 0);
                accO[1][ht] = __builtin_amdgcn_mfma_f32_16x16x16f16(av, pf[1][st], accO[1][ht], 0, 0, 0);
            }
        }
    }

    // epilogue: per t-tile, transpose O^T (h=quad*4+reg, t=l16) via LDS,
    // store f16 partials. Uniform control flow -> barriers are safe.
    for (int tt = 0; tt < 2; tt++) {
        __syncthreads();
        float* ep = (float*)smem + wid * 2048;     // 16t x 128h per wave (8 KB)
        for (int ht = 0; ht < 8; ht++)
            for (int r = 0; r < 4; r++)
                ep[(ht * 16 + quad * 4 + r) * 16 + l16] = accO[tt][ht][r];
        __syncthreads();
        {
            int t = lane >> 2, hq = lane & 3;
            int tgl = tw + tt * 16 + t;
            f16* dst = pO + ((size_t)(c * Bn + b) * Tn + tgl) * Hn + hq * 32;
            for (int g = 0; g < 4; g++) {          // 4 x f16x8 = 32 h
                f16x8 v;
                for (int j = 0; j < 8; j++)
                    v[j] = (f16)ep[(hq * 32 + g * 8 + j) * 16 + t];
                *(f16x8*)(dst + g * 8) = v;
            }
        }
        if (quad == 0) {
            pm[(c * Bn + b) * Tn + tw + tt * 16 + l16] = m_i[tt];
            pl[(c * Bn + b) * Tn + tw + tt * 16 + l16] = l_i[tt];
        }
    }
}

// ---------------------------------------------------------------------------
// Kernel 4: merge SCHUNKS partials. thread -> (b,t, 32 h's). Coalesced.
// ---------------------------------------------------------------------------
__global__ __launch_bounds__(256) void merge_kernel(const f16* __restrict__ pO,
                                                    const float* __restrict__ pm,
                                                    const float* __restrict__ pl,
                                                    float* __restrict__ out) {
    int gid = blockIdx.x * 256 + threadIdx.x;   // 0..32767
    int tg = gid >> 2;                          // b*Tn + t  (0..8191)
    int hq = gid & 3;
    float mc[SCHUNKS], lc[SCHUNKS];
    float M = -3e38f;
    for (int cI = 0; cI < SCHUNKS; cI++) {
        mc[cI] = pm[cI * (Bn * Tn) + tg];
        lc[cI] = pl[cI * (Bn * Tn) + tg];
        M = fmaxf(M, mc[cI]);
    }
    float L = 0.0f, wc[SCHUNKS];
    for (int cI = 0; cI < SCHUNKS; cI++) {
        wc[cI] = __expf(mc[cI] - M);
        L += wc[cI] * lc[cI];
    }
    float inv = 1.0f / L;
    float o[32] = {};
    for (int cI = 0; cI < SCHUNKS; cI++) {
        const f16* src = pO + ((size_t)cI * Bn * Tn + tg) * Hn + hq * 32;
        float w = wc[cI];
        for (int g = 0; g < 4; g++) {
            f16x8 v = *(const f16x8*)(src + g * 8);
            for (int j = 0; j < 8; j++) o[g * 8 + j] += w * (float)v[j];
        }
    }
    float* dst = out + (size_t)tg * Hn + hq * 32;
    for (int g = 0; g < 8; g++) {
        float4 v = { o[g*4+0] * inv, o[g*4+1] * inv, o[g*4+2] * inv, o[g*4+3] * inv };
        *(float4*)(dst + g * 4) = v;
    }
}

extern "C" void kernel_launch(void* const* d_in, const int* in_sizes, int n_in,
                              void* d_out, int out_size, void* d_ws, size_t ws_size,
                              hipStream_t stream) {
    const float* X  = (const float*)d_in[0];
    const float* Wk = (const float*)d_in[1];
    const float* bk = (const float*)d_in[2];
    const float* Wq = (const float*)d_in[3];
    const float* bq = (const float*)d_in[4];
    const float* Wv = (const float*)d_in[5];
    const float* bv = (const float*)d_in[6];
    float* out = (float*)d_out;

    // ws layout (bytes):
    //   Wt [384][1024] f16        @ 0           (786,432)
    //   pk [8192][128] f16        @ 786,432     (2,097,152)
    //   pq [8192][128] f16        @ 2,883,584   (2,097,152)
    //   vT [4][128][2048] f16     @ 4,980,736   (2,097,152)
    //   pO [8][4][2048][128] f16  @ 7,077,888   (16,777,216)
    //   pm [8][4][2048] f32       @ 23,855,104  (262,144)
    //   pl [8][4][2048] f32       @ 24,117,248  (262,144)   total ~24.4 MB
    char* base = (char*)d_ws;
    f16*   Wt = (f16*)(base);
    f16*   pk = (f16*)(base + 786432);
    f16*   pq = (f16*)(base + 2883584);
    f16*   vT = (f16*)(base + 4980736);
    f16*   pO = (f16*)(base + 7077888);
    float* pm = (float*)(base + 23855104);
    float* pl = (float*)(base + 24117248);

    prep_w<<<dim3(512, 3), 256, 0, stream>>>(Wk, Wq, Wv, Wt);
    qkv_gemm<<<dim3(Mn / 64, 2), 512, 0, stream>>>(X, Wt, bk, bq, bv, pk, pq, vT);
    attn_kernel<<<dim3(Tn / 128, SCHUNKS, Bn), 256, 0, stream>>>(pk, pq, vT, pO, pm, pl);
    merge_kernel<<<dim3(128), 256, 0, stream>>>(pO, pm, pl, out);
}

// Round 9
// 129.089 us; speedup vs baseline: 1.4129x; 1.0145x over previous
//
#include <hip/hip_runtime.h>
#include <hip/hip_bf16.h>

// Problem constants: B=4, T=2048, C(n_embd)=1024, H(head)=128
#define Bn 4
#define Tn 2048
#define Cn 1024
#define Hn 128
#define Mn (Bn*Tn)   // 8192 rows of X
#define SCHUNKS 8    // s-split across blocks in attention
#define SCHUNK  (Tn/SCHUNKS)   // 256

typedef _Float16 f16;
typedef __attribute__((ext_vector_type(4))) _Float16 f16x4;  // 2 VGPRs
typedef __attribute__((ext_vector_type(8))) _Float16 f16x8;  // 4 VGPRs
typedef __attribute__((ext_vector_type(4))) float f32x4;

// ---------------------------------------------------------------------------
// Kernel 1: transpose + convert weights [C][H] fp32 -> fused [3*H][C] fp16.
// ---------------------------------------------------------------------------
__global__ void prep_w(const float* __restrict__ Wk, const float* __restrict__ Wq,
                       const float* __restrict__ Wv, f16* __restrict__ Wt) {
    const int w = blockIdx.y;
    const float* W = (w == 0) ? Wk : (w == 1) ? Wq : Wv;
    int idx = blockIdx.x * 256 + threadIdx.x;      // 0 .. C*H-1
    int c = idx >> 7;
    int h = idx & 127;
    Wt[w * (Cn * Hn) + h * Cn + c] = (f16)W[idx];  // row n = w*128+h, len Cn
}

// ---------------------------------------------------------------------------
// Kernel 2: fused QKV projection.  [k|q|v] = X @ [Wk|Wq|Wv] + bias, k *= 1/32.
// grid = (Mn/64, 2) = 256 blocks, 512 threads (8 waves). BM=64, BN=192, BK=64.
// Epilogue via LDS: k/q row-major f16x8 stores; v stored transposed into vT.
// ---------------------------------------------------------------------------
__global__ __launch_bounds__(512) void qkv_gemm(const float* __restrict__ X,
                                                const f16* __restrict__ Wt,
                                                const float* __restrict__ bk,
                                                const float* __restrict__ bq,
                                                const float* __restrict__ bv,
                                                f16* __restrict__ pk,
                                                f16* __restrict__ pq,
                                                f16* __restrict__ vT) {
    __shared__ __align__(16) char smem[36864];
    f16* As = (f16*)smem;                  // [64][72]
    f16* Bs = (f16*)(smem + 9216);         // [192][72]

    const int tid  = threadIdx.x;
    const int r0   = blockIdx.x * 64;
    const int ns   = blockIdx.y;           // 0: n 0..191, 1: n 192..383
    const int lane = tid & 63, wid = tid >> 6;
    const int quad = lane >> 4, l16 = lane & 15;
    const int wm = wid >> 2, wn = wid & 3;

    f32x4 acc[2][3] = {};

    for (int k0 = 0; k0 < Cn; k0 += 64) {
        for (int i = 0; i < 2; i++) {
            int ci = tid + 512 * i;
            int row = ci >> 4, c4 = ci & 15;
            float4 x = *(const float4*)(X + (r0 + row) * Cn + k0 + c4 * 4);
            f16x4 v = { (f16)x.x, (f16)x.y, (f16)x.z, (f16)x.w };
            *(f16x4*)(&As[row * 72 + c4 * 4]) = v;
        }
        for (int i = 0; i < 3; i++) {
            int ci = tid + 512 * i;
            int row = ci >> 3, cc = ci & 7;
            *(f16x8*)(&Bs[row * 72 + cc * 8]) =
                *(const f16x8*)(Wt + (ns * 192 + row) * Cn + k0 + cc * 8);
        }
        __syncthreads();
        for (int ks = 0; ks < 2; ks++) {
            int kk = ks * 32;
            f16x8 af[2], bf[3];
            for (int mt = 0; mt < 2; mt++)
                af[mt] = *(const f16x8*)(&As[(wm * 32 + mt * 16 + l16) * 72 + kk + quad * 8]);
            for (int nt = 0; nt < 3; nt++)
                bf[nt] = *(const f16x8*)(&Bs[(wn * 48 + nt * 16 + l16) * 72 + kk + quad * 8]);
            for (int mt = 0; mt < 2; mt++)
                for (int nt = 0; nt < 3; nt++)
                    acc[mt][nt] = __builtin_amdgcn_mfma_f32_16x16x32_f16(
                        af[mt], bf[nt], acc[mt][nt], 0, 0, 0);
        }
        __syncthreads();
    }

    // ---- epilogue via LDS: E [64 rows][200] f16 (reuses staging smem) ----
    f16* E = (f16*)smem;
    for (int nt = 0; nt < 3; nt++) {
        int n0 = ns * 192 + wn * 48 + nt * 16;
        int wsel = n0 >> 7;
        int col = (n0 & 127) + l16;
        const float* bias = (wsel == 0) ? bk : (wsel == 1) ? bq : bv;
        float bval = bias[col];
        float scale = (wsel == 0) ? 0.03125f : 1.0f;   // fold C^-0.5 into k
        for (int mt = 0; mt < 2; mt++)
            for (int r = 0; r < 4; r++) {
                int mrow = wm * 32 + mt * 16 + quad * 4 + r;
                E[mrow * 200 + wn * 48 + nt * 16 + l16] =
                    (f16)((acc[mt][nt][r] + bval) * scale);
            }
    }
    __syncthreads();

    if (ns == 0) {
        for (int i = 0; i < 3; i++) {
            int ci = tid + 512 * i;
            int row = ci / 24, c = ci % 24;
            f16x8 v = *(const f16x8*)(&E[row * 200 + c * 8]);
            int gn = c * 8;                      // 0..191
            f16* dst = (gn < 128) ? (pk + (r0 + row) * Hn + gn)
                                  : (pq + (r0 + row) * Hn + (gn - 128));
            *(f16x8*)dst = v;
        }
    } else {
        {
            int ci = tid;
            int row = ci >> 3, c = ci & 7;
            f16x8 v = *(const f16x8*)(&E[row * 200 + c * 8]);
            *(f16x8*)(pq + (r0 + row) * Hn + 64 + c * 8) = v;
        }
        int b = r0 >> 11, sg = r0 & 2047;
        for (int i = 0; i < 2; i++) {
            int ci = tid + 512 * i;
            int h = ci >> 3, sc = ci & 7;
            f16x8 v;
            for (int j = 0; j < 8; j++)
                v[j] = E[(sc * 8 + j) * 200 + 64 + h];
            *(f16x8*)(vT + (b * Hn + h) * Tn + sg + sc * 8) = v;
        }
    }
}

// ---------------------------------------------------------------------------
// Kernel 3: flash attention over an s-chunk. 128 t per block (32 t/wave, two
// 16-t tiles). Single LDS buffer (R6-proven; a correct double buffer needs
// 71680 B > 64 KB -- R7/R8's dbuf overlapped buffers and corrupted LDS).
// Register prefetch of next iter's q/vT hides global latency behind compute.
// grid = (Tn/128, SCHUNKS, Bn) = (16,8,4) = 512 blocks, 256 threads (4 waves).
// ---------------------------------------------------------------------------
__global__ __launch_bounds__(256, 2) void attn_kernel(const f16* __restrict__ pk,
                                                      const f16* __restrict__ pq,
                                                      const f16* __restrict__ vT,
                                                      f16* __restrict__ pO,
                                                      float* __restrict__ pm,
                                                      float* __restrict__ pl) {
    __shared__ __align__(16) char smem[36864];
    f16* Bq = (f16*)smem;                 // [64][136] q rows (s-major), 17408 B
    f16* Vt = (f16*)(smem + 17408);       // [128][72]  vT tile (h-major), 18432 B

    const int tid  = threadIdx.x;
    const int tblk = blockIdx.x, c = blockIdx.y, b = blockIdx.z;
    const int t0   = tblk * 128;
    const int lane = tid & 63, wid = tid >> 6;
    const int quad = lane >> 4, l16 = lane & 15;
    const int tw   = t0 + wid * 32;                // wave's 32-t base

    const f16* kp = pk + b * Tn * Hn;
    const f16* qp = pq + b * Tn * Hn;
    const f16* vp = vT + b * Hn * Tn;

    // hoist k fragments: 2 t-tiles x 4 K32-steps, B[n=t(l16)][k=h]
    f16x8 kfr[2][4];
    for (int tt = 0; tt < 2; tt++)
        for (int ks = 0; ks < 4; ks++)
            kfr[tt][ks] = *(const f16x8*)(kp + (tw + tt * 16 + l16) * Hn + ks * 32 + quad * 8);

    float m_i[2] = { -3e38f, -3e38f }, l_i[2] = { 0.0f, 0.0f };
    f32x4 accO[2][8] = {};

    // prefetch iter 0
    f16x8 qreg[4], vreg[4];
    {
        const int s0 = c * SCHUNK;
        for (int i = 0; i < 4; i++) {
            int ci = tid + 256 * i;
            qreg[i] = *(const f16x8*)(qp + (s0 + (ci >> 4)) * Hn + (ci & 15) * 8);
            vreg[i] = *(const f16x8*)(vp + (ci >> 3) * Tn + s0 + (ci & 7) * 8);
        }
    }

    for (int si = 0; si < SCHUNK / 64; si++) {
        __syncthreads();   // LDS free (previous iter's reads done)
        for (int i = 0; i < 4; i++) {
            int ci = tid + 256 * i;
            *(f16x8*)(&Bq[(ci >> 4) * 136 + (ci & 15) * 8]) = qreg[i];
            *(f16x8*)(&Vt[(ci >> 3) * 72 + (ci & 7) * 8]) = vreg[i];
        }
        __syncthreads();
        if (si + 1 < SCHUNK / 64) {
            const int s1 = c * SCHUNK + (si + 1) * 64;
            for (int i = 0; i < 4; i++) {
                int ci = tid + 256 * i;
                qreg[i] = *(const f16x8*)(qp + (s1 + (ci >> 4)) * Hn + (ci & 15) * 8);
                vreg[i] = *(const f16x8*)(vp + (ci >> 3) * Tn + s1 + (ci & 7) * 8);
            }
        }

        // S^T tiles: A = q rows (m=s), B = k frags (n=t). af shared across tt.
        f32x4 accS[2][4] = {};
        for (int ks = 0; ks < 4; ks++) {
            int kk = ks * 32;
            for (int st = 0; st < 4; st++) {
                f16x8 af = *(const f16x8*)(&Bq[(st * 16 + l16) * 136 + kk + quad * 8]);
                accS[0][st] = __builtin_amdgcn_mfma_f32_16x16x32_f16(af, kfr[0][ks], accS[0][st], 0, 0, 0);
                accS[1][st] = __builtin_amdgcn_mfma_f32_16x16x32_f16(af, kfr[1][ks], accS[1][st], 0, 0, 0);
            }
        }

        // online softmax in registers: row = t = l16; s over quad x reg x st.
        f16x4 pf[2][4];
        for (int tt = 0; tt < 2; tt++) {
            float mloc = -3e38f;
            for (int st = 0; st < 4; st++)
                for (int r = 0; r < 4; r++) mloc = fmaxf(mloc, accS[tt][st][r]);
            mloc = fmaxf(mloc, __shfl_xor(mloc, 16));
            mloc = fmaxf(mloc, __shfl_xor(mloc, 32));
            float mnew = fmaxf(m_i[tt], mloc);
            float alpha = __expf(m_i[tt] - mnew);
            m_i[tt] = mnew;
            float psum = 0.0f;
            for (int st = 0; st < 4; st++) {
                f32x4 p;
                for (int r = 0; r < 4; r++) {
                    p[r] = __expf(accS[tt][st][r] - mnew);
                    psum += p[r];
                }
                pf[tt][st] = { (f16)p[0], (f16)p[1], (f16)p[2], (f16)p[3] };
            }
            psum += __shfl_xor(psum, 16);
            psum += __shfl_xor(psum, 32);
            l_i[tt] = l_i[tt] * alpha + psum;
            for (int ht = 0; ht < 8; ht++)
                for (int r = 0; r < 4; r++) accO[tt][ht][r] *= alpha;
        }

        // O^T += Vt . P  (K=16). av shared across tt.
        for (int st = 0; st < 4; st++) {
            for (int ht = 0; ht < 8; ht++) {
                f16x4 av = *(const f16x4*)(&Vt[(ht * 16 + l16) * 72 + st * 16 + quad * 4]);
                accO[0][ht] = __builtin_amdgcn_mfma_f32_16x16x16f16(av, pf[0][st], accO[0][ht], 0, 0, 0);
                accO[1][ht] = __builtin_amdgcn_mfma_f32_16x16x16f16(av, pf[1][st], accO[1][ht], 0, 0, 0);
            }
        }
    }

    // epilogue: per t-tile, transpose O^T (h=quad*4+reg, t=l16) via LDS,
    // store f16 partials. Uniform control flow -> barriers are safe.
    for (int tt = 0; tt < 2; tt++) {
        __syncthreads();
        float* ep = (float*)smem + wid * 2048;     // 16t x 128h per wave (8 KB)
        for (int ht = 0; ht < 8; ht++)
            for (int r = 0; r < 4; r++)
                ep[(ht * 16 + quad * 4 + r) * 16 + l16] = accO[tt][ht][r];
        __syncthreads();
        {
            int t = lane >> 2, hq = lane & 3;
            int tgl = tw + tt * 16 + t;
            f16* dst = pO + ((size_t)(c * Bn + b) * Tn + tgl) * Hn + hq * 32;
            for (int g = 0; g < 4; g++) {          // 4 x f16x8 = 32 h
                f16x8 v;
                for (int j = 0; j < 8; j++)
                    v[j] = (f16)ep[(hq * 32 + g * 8 + j) * 16 + t];
                *(f16x8*)(dst + g * 8) = v;
            }
        }
        if (quad == 0) {
            pm[(c * Bn + b) * Tn + tw + tt * 16 + l16] = m_i[tt];
            pl[(c * Bn + b) * Tn + tw + tt * 16 + l16] = l_i[tt];
        }
    }
}

// ---------------------------------------------------------------------------
// Kernel 4: merge SCHUNKS partials. thread -> (b,t, 8 h's). Coalesced.
// grid = 512 blocks x 256 threads (one thread per (t, 8h) unit).
// ---------------------------------------------------------------------------
__global__ __launch_bounds__(256) void merge_kernel(const f16* __restrict__ pO,
                                                    const float* __restrict__ pm,
                                                    const float* __restrict__ pl,
                                                    float* __restrict__ out) {
    int gid = blockIdx.x * 256 + threadIdx.x;   // 0..131071
    int tg  = gid >> 4;                         // b*Tn + t  (0..8191)
    int hs  = (gid & 15) * 8;                   // 8 h per thread
    float mc[SCHUNKS], lc[SCHUNKS];
    float M = -3e38f;
    for (int cI = 0; cI < SCHUNKS; cI++) {
        mc[cI] = pm[cI * (Bn * Tn) + tg];
        lc[cI] = pl[cI * (Bn * Tn) + tg];
        M = fmaxf(M, mc[cI]);
    }
    float L = 0.0f, wc[SCHUNKS];
    for (int cI = 0; cI < SCHUNKS; cI++) {
        wc[cI] = __expf(mc[cI] - M);
        L += wc[cI] * lc[cI];
    }
    float inv = 1.0f / L;
    float o[8] = {};
    for (int cI = 0; cI < SCHUNKS; cI++) {
        const f16* src = pO + ((size_t)cI * Bn * Tn + tg) * Hn + hs;
        f16x8 v = *(const f16x8*)src;
        float w = wc[cI];
        for (int j = 0; j < 8; j++) o[j] += w * (float)v[j];
    }
    float* dst = out + (size_t)tg * Hn + hs;
    float4 v0 = { o[0] * inv, o[1] * inv, o[2] * inv, o[3] * inv };
    float4 v1 = { o[4] * inv, o[5] * inv, o[6] * inv, o[7] * inv };
    *(float4*)dst = v0;
    *(float4*)(dst + 4) = v1;
}

extern "C" void kernel_launch(void* const* d_in, const int* in_sizes, int n_in,
                              void* d_out, int out_size, void* d_ws, size_t ws_size,
                              hipStream_t stream) {
    const float* X  = (const float*)d_in[0];
    const float* Wk = (const float*)d_in[1];
    const float* bk = (const float*)d_in[2];
    const float* Wq = (const float*)d_in[3];
    const float* bq = (const float*)d_in[4];
    const float* Wv = (const float*)d_in[5];
    const float* bv = (const float*)d_in[6];
    float* out = (float*)d_out;

    // ws layout (bytes):
    //   Wt [384][1024] f16        @ 0           (786,432)
    //   pk [8192][128] f16        @ 786,432     (2,097,152)
    //   pq [8192][128] f16        @ 2,883,584   (2,097,152)
    //   vT [4][128][2048] f16     @ 4,980,736   (2,097,152)
    //   pO [8][4][2048][128] f16  @ 7,077,888   (16,777,216)
    //   pm [8][4][2048] f32       @ 23,855,104  (262,144)
    //   pl [8][4][2048] f32       @ 24,117,248  (262,144)   total ~24.4 MB
    char* base = (char*)d_ws;
    f16*   Wt = (f16*)(base);
    f16*   pk = (f16*)(base + 786432);
    f16*   pq = (f16*)(base + 2883584);
    f16*   vT = (f16*)(base + 4980736);
    f16*   pO = (f16*)(base + 7077888);
    float* pm = (float*)(base + 23855104);
    float* pl = (float*)(base + 24117248);

    prep_w<<<dim3(512, 3), 256, 0, stream>>>(Wk, Wq, Wv, Wt);
    qkv_gemm<<<dim3(Mn / 64, 2), 512, 0, stream>>>(X, Wt, bk, bq, bv, pk, pq, vT);
    attn_kernel<<<dim3(Tn / 128, SCHUNKS, Bn), 256, 0, stream>>>(pk, pq, vT, pO, pm, pl);
    merge_kernel<<<dim3(512), 256, 0, stream>>>(pO, pm, pl, out);
}

// Round 10
// 126.933 us; speedup vs baseline: 1.4369x; 1.0170x over previous
//
#include <hip/hip_runtime.h>
#include <hip/hip_bf16.h>

// Problem constants: B=4, T=2048, C(n_embd)=1024, H(head)=128
#define Bn 4
#define Tn 2048
#define Cn 1024
#define Hn 128
#define Mn (Bn*Tn)   // 8192 rows of X
#define SCHUNKS 4    // s-split across blocks in attention
#define SCHUNK  (Tn/SCHUNKS)   // 512

typedef _Float16 f16;
typedef __attribute__((ext_vector_type(4))) _Float16 f16x4;  // 2 VGPRs
typedef __attribute__((ext_vector_type(8))) _Float16 f16x8;  // 4 VGPRs
typedef __attribute__((ext_vector_type(4))) float f32x4;

// ---------------------------------------------------------------------------
// Kernel 1: transpose + convert weights [C][H] fp32 -> fused [3*H][C] fp16.
// LDS 64x64 tile transpose: coalesced float4 reads AND f16x8 (128B-sector)
// writes. grid = (Cn/64, Hn/64, 3) = (16,2,3) = 96 blocks, 256 threads.
// ---------------------------------------------------------------------------
__global__ __launch_bounds__(256) void prep_w(const float* __restrict__ Wk,
                                              const float* __restrict__ Wq,
                                              const float* __restrict__ Wv,
                                              f16* __restrict__ Wt) {
    __shared__ __align__(16) f16 T[64 * 72];   // [c][h], stride 72
    const int w = blockIdx.z;
    const float* W = (w == 0) ? Wk : (w == 1) ? Wq : Wv;
    const int c0 = blockIdx.x * 64, h0 = blockIdx.y * 64;
    const int tid = threadIdx.x;

    // read 64c x 64h fp32: 1024 float4, 4/thread; convert to f16 in LDS
    for (int i = 0; i < 4; i++) {
        int ci = tid + 256 * i;
        int row = ci >> 4, c4 = ci & 15;
        float4 x = *(const float4*)(W + (c0 + row) * Hn + h0 + c4 * 4);
        f16x4 v = { (f16)x.x, (f16)x.y, (f16)x.z, (f16)x.w };
        *(f16x4*)(&T[row * 72 + c4 * 4]) = v;
    }
    __syncthreads();
    // write 64h x 64c as f16x8 chunks: 512 chunks, 2/thread
    for (int i = 0; i < 2; i++) {
        int ci = tid + 256 * i;
        int h = ci >> 3, cc = ci & 7;
        f16x8 v;
        for (int j = 0; j < 8; j++) v[j] = T[(cc * 8 + j) * 72 + h];
        *(f16x8*)(Wt + (w * Hn + h0 + h) * Cn + c0 + cc * 8) = v;
    }
}

// ---------------------------------------------------------------------------
// Kernel 2: fused QKV projection.  [k|q|v] = X @ [Wk|Wq|Wv] + bias, k *= 1/32.
// grid = (Mn/64, 2) = 256 blocks, 512 threads (8 waves). BM=64, BN=192, BK=64.
// Epilogue via LDS: k/q row-major f16x8 stores; v stored transposed into vT.
// ---------------------------------------------------------------------------
__global__ __launch_bounds__(512) void qkv_gemm(const float* __restrict__ X,
                                                const f16* __restrict__ Wt,
                                                const float* __restrict__ bk,
                                                const float* __restrict__ bq,
                                                const float* __restrict__ bv,
                                                f16* __restrict__ pk,
                                                f16* __restrict__ pq,
                                                f16* __restrict__ vT) {
    __shared__ __align__(16) char smem[36864];
    f16* As = (f16*)smem;                  // [64][72]
    f16* Bs = (f16*)(smem + 9216);         // [192][72]

    const int tid  = threadIdx.x;
    const int r0   = blockIdx.x * 64;
    const int ns   = blockIdx.y;           // 0: n 0..191, 1: n 192..383
    const int lane = tid & 63, wid = tid >> 6;
    const int quad = lane >> 4, l16 = lane & 15;
    const int wm = wid >> 2, wn = wid & 3;

    f32x4 acc[2][3] = {};

    for (int k0 = 0; k0 < Cn; k0 += 64) {
        for (int i = 0; i < 2; i++) {
            int ci = tid + 512 * i;
            int row = ci >> 4, c4 = ci & 15;
            float4 x = *(const float4*)(X + (r0 + row) * Cn + k0 + c4 * 4);
            f16x4 v = { (f16)x.x, (f16)x.y, (f16)x.z, (f16)x.w };
            *(f16x4*)(&As[row * 72 + c4 * 4]) = v;
        }
        for (int i = 0; i < 3; i++) {
            int ci = tid + 512 * i;
            int row = ci >> 3, cc = ci & 7;
            *(f16x8*)(&Bs[row * 72 + cc * 8]) =
                *(const f16x8*)(Wt + (ns * 192 + row) * Cn + k0 + cc * 8);
        }
        __syncthreads();
        for (int ks = 0; ks < 2; ks++) {
            int kk = ks * 32;
            f16x8 af[2], bf[3];
            for (int mt = 0; mt < 2; mt++)
                af[mt] = *(const f16x8*)(&As[(wm * 32 + mt * 16 + l16) * 72 + kk + quad * 8]);
            for (int nt = 0; nt < 3; nt++)
                bf[nt] = *(const f16x8*)(&Bs[(wn * 48 + nt * 16 + l16) * 72 + kk + quad * 8]);
            for (int mt = 0; mt < 2; mt++)
                for (int nt = 0; nt < 3; nt++)
                    acc[mt][nt] = __builtin_amdgcn_mfma_f32_16x16x32_f16(
                        af[mt], bf[nt], acc[mt][nt], 0, 0, 0);
        }
        __syncthreads();
    }

    // ---- epilogue via LDS: E [64 rows][200] f16 (reuses staging smem) ----
    f16* E = (f16*)smem;
    for (int nt = 0; nt < 3; nt++) {
        int n0 = ns * 192 + wn * 48 + nt * 16;
        int wsel = n0 >> 7;
        int col = (n0 & 127) + l16;
        const float* bias = (wsel == 0) ? bk : (wsel == 1) ? bq : bv;
        float bval = bias[col];
        float scale = (wsel == 0) ? 0.03125f : 1.0f;   // fold C^-0.5 into k
        for (int mt = 0; mt < 2; mt++)
            for (int r = 0; r < 4; r++) {
                int mrow = wm * 32 + mt * 16 + quad * 4 + r;
                E[mrow * 200 + wn * 48 + nt * 16 + l16] =
                    (f16)((acc[mt][nt][r] + bval) * scale);
            }
    }
    __syncthreads();

    if (ns == 0) {
        for (int i = 0; i < 3; i++) {
            int ci = tid + 512 * i;
            int row = ci / 24, c = ci % 24;
            f16x8 v = *(const f16x8*)(&E[row * 200 + c * 8]);
            int gn = c * 8;                      // 0..191
            f16* dst = (gn < 128) ? (pk + (r0 + row) * Hn + gn)
                                  : (pq + (r0 + row) * Hn + (gn - 128));
            *(f16x8*)dst = v;
        }
    } else {
        {
            int ci = tid;
            int row = ci >> 3, c = ci & 7;
            f16x8 v = *(const f16x8*)(&E[row * 200 + c * 8]);
            *(f16x8*)(pq + (r0 + row) * Hn + 64 + c * 8) = v;
        }
        int b = r0 >> 11, sg = r0 & 2047;
        for (int i = 0; i < 2; i++) {
            int ci = tid + 512 * i;
            int h = ci >> 3, sc = ci & 7;
            f16x8 v;
            for (int j = 0; j < 8; j++)
                v[j] = E[(sc * 8 + j) * 200 + 64 + h];
            *(f16x8*)(vT + (b * Hn + h) * Tn + sg + sc * 8) = v;
        }
    }
}

// ---------------------------------------------------------------------------
// Kernel 3: flash attention over an s-chunk. 128 t per block (32 t/wave, two
// 16-t tiles). Single LDS buffer (R6-proven). Register prefetch of next
// iter's q/vT hides global latency behind compute.
// grid = (Tn/128, SCHUNKS, Bn) = (16,4,4) = 256 blocks, 256 threads (4 waves).
// Per-CU LDS work is invariant in SCHUNKS; 4 halves pO -> merge traffic.
// ---------------------------------------------------------------------------
__global__ __launch_bounds__(256, 2) void attn_kernel(const f16* __restrict__ pk,
                                                      const f16* __restrict__ pq,
                                                      const f16* __restrict__ vT,
                                                      f16* __restrict__ pO,
                                                      float* __restrict__ pm,
                                                      float* __restrict__ pl) {
    __shared__ __align__(16) char smem[36864];
    f16* Bq = (f16*)smem;                 // [64][136] q rows (s-major), 17408 B
    f16* Vt = (f16*)(smem + 17408);       // [128][72]  vT tile (h-major), 18432 B

    const int tid  = threadIdx.x;
    const int tblk = blockIdx.x, c = blockIdx.y, b = blockIdx.z;
    const int t0   = tblk * 128;
    const int lane = tid & 63, wid = tid >> 6;
    const int quad = lane >> 4, l16 = lane & 15;
    const int tw   = t0 + wid * 32;                // wave's 32-t base

    const f16* kp = pk + b * Tn * Hn;
    const f16* qp = pq + b * Tn * Hn;
    const f16* vp = vT + b * Hn * Tn;

    // hoist k fragments: 2 t-tiles x 4 K32-steps, B[n=t(l16)][k=h]
    f16x8 kfr[2][4];
    for (int tt = 0; tt < 2; tt++)
        for (int ks = 0; ks < 4; ks++)
            kfr[tt][ks] = *(const f16x8*)(kp + (tw + tt * 16 + l16) * Hn + ks * 32 + quad * 8);

    float m_i[2] = { -3e38f, -3e38f }, l_i[2] = { 0.0f, 0.0f };
    f32x4 accO[2][8] = {};

    // prefetch iter 0
    f16x8 qreg[4], vreg[4];
    {
        const int s0 = c * SCHUNK;
        for (int i = 0; i < 4; i++) {
            int ci = tid + 256 * i;
            qreg[i] = *(const f16x8*)(qp + (s0 + (ci >> 4)) * Hn + (ci & 15) * 8);
            vreg[i] = *(const f16x8*)(vp + (ci >> 3) * Tn + s0 + (ci & 7) * 8);
        }
    }

    for (int si = 0; si < SCHUNK / 64; si++) {
        __syncthreads();   // LDS free (previous iter's reads done)
        for (int i = 0; i < 4; i++) {
            int ci = tid + 256 * i;
            *(f16x8*)(&Bq[(ci >> 4) * 136 + (ci & 15) * 8]) = qreg[i];
            *(f16x8*)(&Vt[(ci >> 3) * 72 + (ci & 7) * 8]) = vreg[i];
        }
        __syncthreads();
        if (si + 1 < SCHUNK / 64) {
            const int s1 = c * SCHUNK + (si + 1) * 64;
            for (int i = 0; i < 4; i++) {
                int ci = tid + 256 * i;
                qreg[i] = *(const f16x8*)(qp + (s1 + (ci >> 4)) * Hn + (ci & 15) * 8);
                vreg[i] = *(const f16x8*)(vp + (ci >> 3) * Tn + s1 + (ci & 7) * 8);
            }
        }

        // S^T tiles: A = q rows (m=s), B = k frags (n=t). af shared across tt.
        f32x4 accS[2][4] = {};
        for (int ks = 0; ks < 4; ks++) {
            int kk = ks * 32;
            for (int st = 0; st < 4; st++) {
                f16x8 af = *(const f16x8*)(&Bq[(st * 16 + l16) * 136 + kk + quad * 8]);
                accS[0][st] = __builtin_amdgcn_mfma_f32_16x16x32_f16(af, kfr[0][ks], accS[0][st], 0, 0, 0);
                accS[1][st] = __builtin_amdgcn_mfma_f32_16x16x32_f16(af, kfr[1][ks], accS[1][st], 0, 0, 0);
            }
        }

        // online softmax in registers: row = t = l16; s over quad x reg x st.
        f16x4 pf[2][4];
        for (int tt = 0; tt < 2; tt++) {
            float mloc = -3e38f;
            for (int st = 0; st < 4; st++)
                for (int r = 0; r < 4; r++) mloc = fmaxf(mloc, accS[tt][st][r]);
            mloc = fmaxf(mloc, __shfl_xor(mloc, 16));
            mloc = fmaxf(mloc, __shfl_xor(mloc, 32));
            float mnew = fmaxf(m_i[tt], mloc);
            float alpha = __expf(m_i[tt] - mnew);
            m_i[tt] = mnew;
            float psum = 0.0f;
            for (int st = 0; st < 4; st++) {
                f32x4 p;
                for (int r = 0; r < 4; r++) {
                    p[r] = __expf(accS[tt][st][r] - mnew);
                    psum += p[r];
                }
                pf[tt][st] = { (f16)p[0], (f16)p[1], (f16)p[2], (f16)p[3] };
            }
            psum += __shfl_xor(psum, 16);
            psum += __shfl_xor(psum, 32);
            l_i[tt] = l_i[tt] * alpha + psum;
            for (int ht = 0; ht < 8; ht++)
                for (int r = 0; r < 4; r++) accO[tt][ht][r] *= alpha;
        }

        // O^T += Vt . P  (K=16). av shared across tt.
        for (int st = 0; st < 4; st++) {
            for (int ht = 0; ht < 8; ht++) {
                f16x4 av = *(const f16x4*)(&Vt[(ht * 16 + l16) * 72 + st * 16 + quad * 4]);
                accO[0][ht] = __builtin_amdgcn_mfma_f32_16x16x16f16(av, pf[0][st], accO[0][ht], 0, 0, 0);
                accO[1][ht] = __builtin_amdgcn_mfma_f32_16x16x16f16(av, pf[1][st], accO[1][ht], 0, 0, 0);
            }
        }
    }

    // epilogue: per t-tile, transpose O^T (h=quad*4+reg, t=l16) via LDS,
    // store f16 partials. Uniform control flow -> barriers are safe.
    for (int tt = 0; tt < 2; tt++) {
        __syncthreads();
        float* ep = (float*)smem + wid * 2048;     // 16t x 128h per wave (8 KB)
        for (int ht = 0; ht < 8; ht++)
            for (int r = 0; r < 4; r++)
                ep[(ht * 16 + quad * 4 + r) * 16 + l16] = accO[tt][ht][r];
        __syncthreads();
        {
            int t = lane >> 2, hq = lane & 3;
            int tgl = tw + tt * 16 + t;
            f16* dst = pO + ((size_t)(c * Bn + b) * Tn + tgl) * Hn + hq * 32;
            for (int g = 0; g < 4; g++) {          // 4 x f16x8 = 32 h
                f16x8 v;
                for (int j = 0; j < 8; j++)
                    v[j] = (f16)ep[(hq * 32 + g * 8 + j) * 16 + t];
                *(f16x8*)(dst + g * 8) = v;
            }
        }
        if (quad == 0) {
            pm[(c * Bn + b) * Tn + tw + tt * 16 + l16] = m_i[tt];
            pl[(c * Bn + b) * Tn + tw + tt * 16 + l16] = l_i[tt];
        }
    }
}

// ---------------------------------------------------------------------------
// Kernel 4: merge SCHUNKS partials. thread -> (b,t, 8 h's). Coalesced.
// grid = 512 blocks x 256 threads (one thread per (t, 8h) unit).
// ---------------------------------------------------------------------------
__global__ __launch_bounds__(256) void merge_kernel(const f16* __restrict__ pO,
                                                    const float* __restrict__ pm,
                                                    const float* __restrict__ pl,
                                                    float* __restrict__ out) {
    int gid = blockIdx.x * 256 + threadIdx.x;   // 0..131071
    int tg  = gid >> 4;                         // b*Tn + t  (0..8191)
    int hs  = (gid & 15) * 8;                   // 8 h per thread
    float mc[SCHUNKS], lc[SCHUNKS];
    float M = -3e38f;
    for (int cI = 0; cI < SCHUNKS; cI++) {
        mc[cI] = pm[cI * (Bn * Tn) + tg];
        lc[cI] = pl[cI * (Bn * Tn) + tg];
        M = fmaxf(M, mc[cI]);
    }
    float L = 0.0f, wc[SCHUNKS];
    for (int cI = 0; cI < SCHUNKS; cI++) {
        wc[cI] = __expf(mc[cI] - M);
        L += wc[cI] * lc[cI];
    }
    float inv = 1.0f / L;
    float o[8] = {};
    for (int cI = 0; cI < SCHUNKS; cI++) {
        const f16* src = pO + ((size_t)cI * Bn * Tn + tg) * Hn + hs;
        f16x8 v = *(const f16x8*)src;
        float w = wc[cI];
        for (int j = 0; j < 8; j++) o[j] += w * (float)v[j];
    }
    float* dst = out + (size_t)tg * Hn + hs;
    float4 v0 = { o[0] * inv, o[1] * inv, o[2] * inv, o[3] * inv };
    float4 v1 = { o[4] * inv, o[5] * inv, o[6] * inv, o[7] * inv };
    *(float4*)dst = v0;
    *(float4*)(dst + 4) = v1;
}

extern "C" void kernel_launch(void* const* d_in, const int* in_sizes, int n_in,
                              void* d_out, int out_size, void* d_ws, size_t ws_size,
                              hipStream_t stream) {
    const float* X  = (const float*)d_in[0];
    const float* Wk = (const float*)d_in[1];
    const float* bk = (const float*)d_in[2];
    const float* Wq = (const float*)d_in[3];
    const float* bq = (const float*)d_in[4];
    const float* Wv = (const float*)d_in[5];
    const float* bv = (const float*)d_in[6];
    float* out = (float*)d_out;

    // ws layout (bytes):
    //   Wt [384][1024] f16        @ 0           (786,432)
    //   pk [8192][128] f16        @ 786,432     (2,097,152)
    //   pq [8192][128] f16        @ 2,883,584   (2,097,152)
    //   vT [4][128][2048] f16     @ 4,980,736   (2,097,152)
    //   pO [4][4][2048][128] f16  @ 7,077,888   (8,388,608)
    //   pm [4][4][2048] f32       @ 15,466,496  (131,072)
    //   pl [4][4][2048] f32       @ 15,597,568  (131,072)   total ~15.7 MB
    char* base = (char*)d_ws;
    f16*   Wt = (f16*)(base);
    f16*   pk = (f16*)(base + 786432);
    f16*   pq = (f16*)(base + 2883584);
    f16*   vT = (f16*)(base + 4980736);
    f16*   pO = (f16*)(base + 7077888);
    float* pm = (float*)(base + 15466496);
    float* pl = (float*)(base + 15597568);

    prep_w<<<dim3(Cn / 64, Hn / 64, 3), 256, 0, stream>>>(Wk, Wq, Wv, Wt);
    qkv_gemm<<<dim3(Mn / 64, 2), 512, 0, stream>>>(X, Wt, bk, bq, bv, pk, pq, vT);
    attn_kernel<<<dim3(Tn / 128, SCHUNKS, Bn), 256, 0, stream>>>(pk, pq, vT, pO, pm, pl);
    merge_kernel<<<dim3(512), 256, 0, stream>>>(pO, pm, pl, out);
}